// Round 1
// baseline (3567.873 us; speedup 1.0000x reference)
//
#include <hip/hip_runtime.h>
#include <math.h>

// ---------------------------------------------------------------------------
// GCN summarizer: 4x (GEMM 128x128 -> normalized-adjacency aggregate + bias
// + relu) -> mean-pool per graph -> dot Wc -> sigmoid.
// Strategy: build dst-CSR (with self loops) once per launch, then gather-based
// aggregation (no float atomics in the hot path).
// ---------------------------------------------------------------------------

__global__ void init_nodes(float* deg, int* cnt, int n) {
    int i = blockIdx.x * blockDim.x + threadIdx.x;
    if (i < n) { deg[i] = 1.0f; cnt[i] = 0; }   // deg starts at 1 (self loop w=1)
}

__global__ void init_graphs(float* gsum, float* gcnt, int g) {
    int i = blockIdx.x * blockDim.x + threadIdx.x;
    if (i < g) { gsum[i] = 0.0f; gcnt[i] = 0.0f; }
}

__global__ void deg_count(const int* __restrict__ dst, const float* __restrict__ ew,
                          float* deg, int* cnt, int E) {
    int e = blockIdx.x * blockDim.x + threadIdx.x;
    if (e < E) {
        int d = dst[e];
        atomicAdd(&deg[d], ew[e]);
        atomicAdd(&cnt[d], 1);
    }
}

__global__ void dinv_k(const float* __restrict__ deg, float* dinv, int n) {
    int i = blockIdx.x * blockDim.x + threadIdx.x;
    if (i < n) dinv[i] = rsqrtf(deg[i]);   // deg >= 1 always (self loop)
}

// two-level exclusive scan over L[i] = cnt[i]+1 (i<N), 0 otherwise; total entries N+1
__global__ __launch_bounds__(1024) void scan1(const int* __restrict__ cnt, int* rowp,
                                              int* bsums, int total, int N) {
    __shared__ int sh[1024];
    int i = blockIdx.x * 1024 + threadIdx.x;
    int v = 0;
    if (i < N) v = cnt[i] + 1;
    sh[threadIdx.x] = v;
    __syncthreads();
    for (int off = 1; off < 1024; off <<= 1) {
        int t = (threadIdx.x >= (unsigned)off) ? sh[threadIdx.x - off] : 0;
        __syncthreads();
        sh[threadIdx.x] += t;
        __syncthreads();
    }
    if (i < total) rowp[i] = sh[threadIdx.x] - v;      // exclusive, pre-offset
    if (threadIdx.x == 1023) bsums[blockIdx.x] = sh[1023];
}

__global__ void scan2(int* bsums, int nb) {
    if (threadIdx.x == 0 && blockIdx.x == 0) {
        int run = 0;
        for (int b = 0; b < nb; ++b) { int t = bsums[b]; bsums[b] = run; run += t; }
    }
}

__global__ __launch_bounds__(1024) void scan3(int* rowp, const int* __restrict__ bsums,
                                              int total) {
    int i = blockIdx.x * 1024 + threadIdx.x;
    if (i < total) rowp[i] += bsums[blockIdx.x];
}

__global__ void selfloop_k(const int* __restrict__ rowp, const float* __restrict__ dinv,
                           int* col, float* val, int* cur, int n) {
    int i = blockIdx.x * blockDim.x + threadIdx.x;
    if (i < n) {
        int p = rowp[i];
        col[p] = i;
        float dv = dinv[i];
        val[p] = dv * dv;        // dinv[i] * 1.0 * dinv[i]
        cur[i] = 1;              // self loop occupies slot 0
    }
}

__global__ void scatter_k(const int* __restrict__ src, const int* __restrict__ dst,
                          const float* __restrict__ ew, const float* __restrict__ dinv,
                          const int* __restrict__ rowp, int* cur, int* col, float* val,
                          int E) {
    int e = blockIdx.x * blockDim.x + threadIdx.x;
    if (e < E) {
        int s = src[e], d = dst[e];
        int p = atomicAdd(&cur[d], 1);
        int idx = rowp[d] + p;
        col[idx] = s;
        val[idx] = dinv[s] * ew[e] * dinv[d];
    }
}

// ---------------------------------------------------------------------------
// GEMM: C[n,128] = A[n,128] @ W[128,128], fp32 vector ALU.
// Block: 256 threads, 64-row tile. W chunk transposed into LDS (XOR-swizzled
// 4-elem granules -> conflict-free b128 reads). A tile reads are wave-broadcast.
// ---------------------------------------------------------------------------
__global__ __launch_bounds__(256) void gemm128(const float* __restrict__ A,
                                               const float* __restrict__ W,
                                               float* __restrict__ C, int n) {
    __shared__ float As[64][32];
    __shared__ float Wt[128][32];
    const int t = threadIdx.x;
    const int wave = t >> 6, lane = t & 63;
    const int row0 = blockIdx.x * 64;
    const int rbase = wave * 16;

    float acc0[16], acc1[16];
#pragma unroll
    for (int i = 0; i < 16; ++i) { acc0[i] = 0.f; acc1[i] = 0.f; }

    for (int kc = 0; kc < 4; ++kc) {
        // stage W^T chunk: Wt[c][kl] = W[kc*32+kl][c], XOR-swizzled granules
#pragma unroll
        for (int i = 0; i < 16; ++i) {
            int idx = t + i * 256;            // 0..4095
            int kl = idx >> 7;                // 0..31
            int c = idx & 127;
            int pos = ((((kl >> 2) ^ (c & 7)) << 2) | (kl & 3));
            Wt[c][pos] = W[(kc * 32 + kl) * 128 + c];
        }
        // stage A tile: As[r][kl] = A[row0+r][kc*32+kl]
#pragma unroll
        for (int i = 0; i < 8; ++i) {
            int idx = t + i * 256;            // 0..2047
            int r = idx >> 5;
            int kl = idx & 31;
            int gr = row0 + r;
            As[r][kl] = (gr < n) ? A[gr * 128 + kc * 32 + kl] : 0.f;
        }
        __syncthreads();
#pragma unroll
        for (int kk = 0; kk < 32; kk += 4) {
            int g = kk >> 2;
            const float4 w0 = *(const float4*)&Wt[lane][(g ^ (lane & 7)) << 2];
            const float4 w1 = *(const float4*)&Wt[lane + 64][(g ^ ((lane + 64) & 7)) << 2];
#pragma unroll
            for (int r = 0; r < 16; ++r) {
                const float4 a = *(const float4*)&As[rbase + r][kk];
                acc0[r] += a.x * w0.x + a.y * w0.y + a.z * w0.z + a.w * w0.w;
                acc1[r] += a.x * w1.x + a.y * w1.y + a.z * w1.z + a.w * w1.w;
            }
        }
        __syncthreads();
    }
#pragma unroll
    for (int r = 0; r < 16; ++r) {
        int gr = row0 + rbase + r;
        if (gr < n) {
            C[gr * 128 + lane] = acc0[r];
            C[gr * 128 + lane + 64] = acc1[r];
        }
    }
}

// ---------------------------------------------------------------------------
// Aggregate: out[v] = relu( sum_e val[e] * tin[col[e]] + bias ), one wave/node,
// lane holds feats {2*lane, 2*lane+1} -> 512 B coalesced gather per edge.
// ---------------------------------------------------------------------------
__global__ __launch_bounds__(256) void aggregate(const float* __restrict__ tin,
                                                 const int* __restrict__ rowp,
                                                 const int* __restrict__ col,
                                                 const float* __restrict__ val,
                                                 const float* __restrict__ bias,
                                                 float* __restrict__ out, int n) {
    int v = blockIdx.x * 4 + (threadIdx.x >> 6);
    int lane = threadIdx.x & 63;
    if (v >= n) return;
    int e0 = rowp[v], e1 = rowp[v + 1];
    float ax = 0.f, ay = 0.f;
    for (int e = e0; e < e1; ++e) {
        int c = col[e];
        float w = val[e];
        float2 hv = *(const float2*)&tin[c * 128 + lane * 2];
        ax += w * hv.x;
        ay += w * hv.y;
    }
    float2 b2 = *(const float2*)&bias[lane * 2];
    float2 r;
    r.x = fmaxf(ax + b2.x, 0.f);
    r.y = fmaxf(ay + b2.y, 0.f);
    *(float2*)&out[v * 128 + lane * 2] = r;
}

// per-node scalar s_v = h_v . Wc, atomically segment-summed per graph
__global__ __launch_bounds__(256) void pool_k(const float* __restrict__ h,
                                              const int* __restrict__ batch,
                                              const float* __restrict__ Wc,
                                              float* gsum, float* gcnt, int n) {
    int v = blockIdx.x * 4 + (threadIdx.x >> 6);
    int lane = threadIdx.x & 63;
    if (v >= n) return;
    float2 hv = *(const float2*)&h[v * 128 + lane * 2];
    float2 wc = *(const float2*)&Wc[lane * 2];
    float p = hv.x * wc.x + hv.y * wc.y;
#pragma unroll
    for (int off = 32; off; off >>= 1) p += __shfl_down(p, off);
    if (lane == 0) {
        int g = batch[v];
        atomicAdd(&gsum[g], p);
        atomicAdd(&gcnt[g], 1.0f);
    }
}

__global__ void final_k(const float* __restrict__ gsum, const float* __restrict__ gcnt,
                        const float* __restrict__ bc, float* out, int G) {
    int g = blockIdx.x * blockDim.x + threadIdx.x;
    if (g < G) {
        float z = gsum[g] / fmaxf(gcnt[g], 1.0f) + bc[0];
        out[g] = 1.0f / (1.0f + expf(-z));
    }
}

extern "C" void kernel_launch(void* const* d_in, const int* in_sizes, int n_in,
                              void* d_out, int out_size, void* d_ws, size_t ws_size,
                              hipStream_t stream) {
    const float* x   = (const float*)d_in[0];
    const int* ei    = (const int*)d_in[1];
    const float* ew  = (const float*)d_in[2];
    const int* batch = (const int*)d_in[3];
    const float* W1 = (const float*)d_in[4];  const float* b1 = (const float*)d_in[5];
    const float* W2 = (const float*)d_in[6];  const float* b2 = (const float*)d_in[7];
    const float* W3 = (const float*)d_in[8];  const float* b3 = (const float*)d_in[9];
    const float* W4 = (const float*)d_in[10]; const float* b4 = (const float*)d_in[11];
    const float* Wc = (const float*)d_in[12]; const float* bc = (const float*)d_in[13];

    const int N = in_sizes[0] / 128;
    const int E = in_sizes[2];
    const int G = out_size;
    const int* src = ei;
    const int* dst = ei + E;

    // workspace carve (re-poisoned to 0xAA every call -> everything read is
    // initialized below)
    char* p = (char*)d_ws;
    auto alloc = [&](size_t bytes) {
        void* q = (void*)p;
        p += (bytes + 255) & ~(size_t)255;
        return q;
    };
    float* deg  = (float*)alloc((size_t)N * 4);
    float* dinv = (float*)alloc((size_t)N * 4);
    int* cnt    = (int*)alloc((size_t)N * 4);
    int* cur    = (int*)alloc((size_t)N * 4);
    int* rowp   = (int*)alloc((size_t)(N + 1) * 4);
    int* bsums  = (int*)alloc(1024 * 4);
    const size_t M = (size_t)E + (size_t)N;
    int* col   = (int*)alloc(M * 4);
    float* val = (float*)alloc(M * 4);
    float* tbuf = (float*)alloc((size_t)N * 128 * 4);
    float* hbuf = (float*)alloc((size_t)N * 128 * 4);
    float* gsum = (float*)alloc((size_t)G * 4);
    float* gcnt = (float*)alloc((size_t)G * 4);

    const int B = 256;
    // --- graph normalization + CSR build ---
    init_nodes<<<(N + B - 1) / B, B, 0, stream>>>(deg, cnt, N);
    init_graphs<<<(G + B - 1) / B, B, 0, stream>>>(gsum, gcnt, G);
    deg_count<<<(E + B - 1) / B, B, 0, stream>>>(dst, ew, deg, cnt, E);
    dinv_k<<<(N + B - 1) / B, B, 0, stream>>>(deg, dinv, N);
    const int total = N + 1;
    const int nb = (total + 1023) / 1024;
    scan1<<<nb, 1024, 0, stream>>>(cnt, rowp, bsums, total, N);
    scan2<<<1, 64, 0, stream>>>(bsums, nb);
    scan3<<<nb, 1024, 0, stream>>>(rowp, bsums, total);
    selfloop_k<<<(N + B - 1) / B, B, 0, stream>>>(rowp, dinv, col, val, cur, N);
    scatter_k<<<(E + B - 1) / B, B, 0, stream>>>(src, dst, ew, dinv, rowp, cur, col, val, E);

    // --- 4 GCN layers: gemm (h@W -> tbuf), aggregate (+bias, relu -> hbuf) ---
    const int ggrid = (N + 63) / 64;
    const int agrid = (N + 3) / 4;
    gemm128<<<ggrid, B, 0, stream>>>(x, W1, tbuf, N);
    aggregate<<<agrid, B, 0, stream>>>(tbuf, rowp, col, val, b1, hbuf, N);
    gemm128<<<ggrid, B, 0, stream>>>(hbuf, W2, tbuf, N);
    aggregate<<<agrid, B, 0, stream>>>(tbuf, rowp, col, val, b2, hbuf, N);
    gemm128<<<ggrid, B, 0, stream>>>(hbuf, W3, tbuf, N);
    aggregate<<<agrid, B, 0, stream>>>(tbuf, rowp, col, val, b3, hbuf, N);
    gemm128<<<ggrid, B, 0, stream>>>(hbuf, W4, tbuf, N);
    aggregate<<<agrid, B, 0, stream>>>(tbuf, rowp, col, val, b4, hbuf, N);

    // --- mean pool + classifier + sigmoid ---
    pool_k<<<agrid, B, 0, stream>>>(hbuf, batch, Wc, gsum, gcnt, N);
    final_k<<<(G + B - 1) / B, B, 0, stream>>>(gsum, gcnt, bc, (float*)d_out, G);
}

// Round 2
// 2107.108 us; speedup vs baseline: 1.6933x; 1.6933x over previous
//
#include <hip/hip_runtime.h>
#include <math.h>

// ---------------------------------------------------------------------------
// GCN summarizer: 4x (GEMM 128x128 -> normalized-adjacency aggregate + bias
// + relu) -> mean-pool per graph -> dot Wc -> sigmoid.
// CSR build (with self loops) once per launch; gather-based aggregation.
// R2: GEMM = register-blocked, scalar-broadcast W (no LDS); aggregate =
//     1 node / 1-wave block so edge metadata goes through s_load.
// ---------------------------------------------------------------------------

__global__ void init_nodes(float* deg, int* cnt, int n) {
    int i = blockIdx.x * blockDim.x + threadIdx.x;
    if (i < n) { deg[i] = 1.0f; cnt[i] = 0; }   // deg starts at 1 (self loop w=1)
}

__global__ void init_graphs(float* gsum, float* gcnt, int g) {
    int i = blockIdx.x * blockDim.x + threadIdx.x;
    if (i < g) { gsum[i] = 0.0f; gcnt[i] = 0.0f; }
}

__global__ void deg_count(const int* __restrict__ dst, const float* __restrict__ ew,
                          float* deg, int* cnt, int E) {
    int e = blockIdx.x * blockDim.x + threadIdx.x;
    if (e < E) {
        int d = dst[e];
        atomicAdd(&deg[d], ew[e]);
        atomicAdd(&cnt[d], 1);
    }
}

__global__ void dinv_k(const float* __restrict__ deg, float* dinv, int n) {
    int i = blockIdx.x * blockDim.x + threadIdx.x;
    if (i < n) dinv[i] = rsqrtf(deg[i]);   // deg >= 1 always (self loop)
}

// two-level exclusive scan over L[i] = cnt[i]+1 (i<N), 0 otherwise; total N+1
__global__ __launch_bounds__(1024) void scan1(const int* __restrict__ cnt, int* rowp,
                                              int* bsums, int total, int N) {
    __shared__ int sh[1024];
    int i = blockIdx.x * 1024 + threadIdx.x;
    int v = 0;
    if (i < N) v = cnt[i] + 1;
    sh[threadIdx.x] = v;
    __syncthreads();
    for (int off = 1; off < 1024; off <<= 1) {
        int t = (threadIdx.x >= (unsigned)off) ? sh[threadIdx.x - off] : 0;
        __syncthreads();
        sh[threadIdx.x] += t;
        __syncthreads();
    }
    if (i < total) rowp[i] = sh[threadIdx.x] - v;      // exclusive, pre-offset
    if (threadIdx.x == 1023) bsums[blockIdx.x] = sh[1023];
}

__global__ void scan2(int* bsums, int nb) {
    if (threadIdx.x == 0 && blockIdx.x == 0) {
        int run = 0;
        for (int b = 0; b < nb; ++b) { int t = bsums[b]; bsums[b] = run; run += t; }
    }
}

__global__ __launch_bounds__(1024) void scan3(int* rowp, const int* __restrict__ bsums,
                                              int total) {
    int i = blockIdx.x * 1024 + threadIdx.x;
    if (i < total) rowp[i] += bsums[blockIdx.x];
}

__global__ void selfloop_k(const int* __restrict__ rowp, const float* __restrict__ dinv,
                           int* col, float* val, int* cur, int n) {
    int i = blockIdx.x * blockDim.x + threadIdx.x;
    if (i < n) {
        int p = rowp[i];
        col[p] = i;
        float dv = dinv[i];
        val[p] = dv * dv;        // dinv[i] * 1.0 * dinv[i]
        cur[i] = 1;              // self loop occupies slot 0
    }
}

__global__ void scatter_k(const int* __restrict__ src, const int* __restrict__ dst,
                          const float* __restrict__ ew, const float* __restrict__ dinv,
                          const int* __restrict__ rowp, int* cur, int* col, float* val,
                          int E) {
    int e = blockIdx.x * blockDim.x + threadIdx.x;
    if (e < E) {
        int s = src[e], d = dst[e];
        int p = atomicAdd(&cur[d], 1);
        int idx = rowp[d] + p;
        col[idx] = s;
        val[idx] = dinv[s] * ew[e] * dinv[d];
    }
}

// ---------------------------------------------------------------------------
// GEMM: C[n,128] = A[n,128] @ W[128,128], fp32 vector ALU.
// grid (ceil(n/256), 4). Thread = 1 row x 32 cols (col group = blockIdx.y).
// W indices are block-uniform -> s_load + v_fmac with SGPR broadcast.
// A row chunk (128 B = 1 cache line) lives in registers; no LDS, no syncs.
// ---------------------------------------------------------------------------
__global__ __launch_bounds__(256) void gemm128(const float* __restrict__ A,
                                               const float* __restrict__ W,
                                               float* __restrict__ C, int n) {
    const int row = blockIdx.x * 256 + threadIdx.x;
    const int c0 = blockIdx.y * 32;
    if (row >= n) return;

    float acc[32];
#pragma unroll
    for (int j = 0; j < 32; ++j) acc[j] = 0.f;

    const float* Ar = A + (size_t)row * 128;

    for (int kc = 0; kc < 4; ++kc) {
        float4 av[8];
#pragma unroll
        for (int i = 0; i < 8; ++i)
            av[i] = *(const float4*)&Ar[kc * 32 + i * 4];
#pragma unroll
        for (int k4 = 0; k4 < 8; ++k4) {
            const float* Wk = W + (size_t)(kc * 32 + k4 * 4) * 128 + c0;
            const float a0 = av[k4].x, a1 = av[k4].y, a2 = av[k4].z, a3 = av[k4].w;
#pragma unroll
            for (int j = 0; j < 32; ++j) {
                acc[j] = fmaf(a0, Wk[j], acc[j]);
                acc[j] = fmaf(a1, Wk[128 + j], acc[j]);
                acc[j] = fmaf(a2, Wk[256 + j], acc[j]);
                acc[j] = fmaf(a3, Wk[384 + j], acc[j]);
            }
        }
    }

    float* Cr = C + (size_t)row * 128 + c0;   // each thread fills its own 128-B line
#pragma unroll
    for (int j = 0; j < 32; j += 4)
        *(float4*)&Cr[j] = make_float4(acc[j], acc[j + 1], acc[j + 2], acc[j + 3]);
}

// ---------------------------------------------------------------------------
// Aggregate: out[v] = relu( sum_e val[e] * tin[col[e]] + bias ). One node per
// 64-thread block -> v = blockIdx.x is provably uniform -> rowp/col/val loads
// are s_load; the 512 B/edge feature gather is the only vector traffic.
// Edge loop unrolled x4 for 4 independent gathers in flight.
// ---------------------------------------------------------------------------
__global__ __launch_bounds__(64) void aggregate(const float* __restrict__ tin,
                                                const int* __restrict__ rowp,
                                                const int* __restrict__ col,
                                                const float* __restrict__ val,
                                                const float* __restrict__ bias,
                                                float* __restrict__ out, int n) {
    const int v = blockIdx.x;
    const int lane = threadIdx.x;          // 0..63, feats {2*lane, 2*lane+1}
    const int e0 = rowp[v], e1 = rowp[v + 1];
    float ax = 0.f, ay = 0.f;
    int e = e0;
    for (; e + 4 <= e1; e += 4) {
        const int c0_ = col[e], c1_ = col[e + 1], c2_ = col[e + 2], c3_ = col[e + 3];
        const float w0 = val[e], w1 = val[e + 1], w2 = val[e + 2], w3 = val[e + 3];
        const float2 h0 = *(const float2*)&tin[(size_t)c0_ * 128 + lane * 2];
        const float2 h1 = *(const float2*)&tin[(size_t)c1_ * 128 + lane * 2];
        const float2 h2 = *(const float2*)&tin[(size_t)c2_ * 128 + lane * 2];
        const float2 h3 = *(const float2*)&tin[(size_t)c3_ * 128 + lane * 2];
        ax = fmaf(w0, h0.x, ax); ay = fmaf(w0, h0.y, ay);
        ax = fmaf(w1, h1.x, ax); ay = fmaf(w1, h1.y, ay);
        ax = fmaf(w2, h2.x, ax); ay = fmaf(w2, h2.y, ay);
        ax = fmaf(w3, h3.x, ax); ay = fmaf(w3, h3.y, ay);
    }
    for (; e < e1; ++e) {
        const int c = col[e];
        const float w = val[e];
        const float2 hv = *(const float2*)&tin[(size_t)c * 128 + lane * 2];
        ax = fmaf(w, hv.x, ax); ay = fmaf(w, hv.y, ay);
    }
    const float2 b2 = *(const float2*)&bias[lane * 2];
    float2 r;
    r.x = fmaxf(ax + b2.x, 0.f);
    r.y = fmaxf(ay + b2.y, 0.f);
    *(float2*)&out[(size_t)v * 128 + lane * 2] = r;
}

// per-node scalar s_v = h_v . Wc, atomically segment-summed per graph
__global__ __launch_bounds__(256) void pool_k(const float* __restrict__ h,
                                              const int* __restrict__ batch,
                                              const float* __restrict__ Wc,
                                              float* gsum, float* gcnt, int n) {
    int v = blockIdx.x * 4 + (threadIdx.x >> 6);
    int lane = threadIdx.x & 63;
    if (v >= n) return;
    float2 hv = *(const float2*)&h[(size_t)v * 128 + lane * 2];
    float2 wc = *(const float2*)&Wc[lane * 2];
    float p = hv.x * wc.x + hv.y * wc.y;
#pragma unroll
    for (int off = 32; off; off >>= 1) p += __shfl_down(p, off);
    if (lane == 0) {
        int g = batch[v];
        atomicAdd(&gsum[g], p);
        atomicAdd(&gcnt[g], 1.0f);
    }
}

__global__ void final_k(const float* __restrict__ gsum, const float* __restrict__ gcnt,
                        const float* __restrict__ bc, float* out, int G) {
    int g = blockIdx.x * blockDim.x + threadIdx.x;
    if (g < G) {
        float z = gsum[g] / fmaxf(gcnt[g], 1.0f) + bc[0];
        out[g] = 1.0f / (1.0f + expf(-z));
    }
}

extern "C" void kernel_launch(void* const* d_in, const int* in_sizes, int n_in,
                              void* d_out, int out_size, void* d_ws, size_t ws_size,
                              hipStream_t stream) {
    const float* x   = (const float*)d_in[0];
    const int* ei    = (const int*)d_in[1];
    const float* ew  = (const float*)d_in[2];
    const int* batch = (const int*)d_in[3];
    const float* W1 = (const float*)d_in[4];  const float* b1 = (const float*)d_in[5];
    const float* W2 = (const float*)d_in[6];  const float* b2 = (const float*)d_in[7];
    const float* W3 = (const float*)d_in[8];  const float* b3 = (const float*)d_in[9];
    const float* W4 = (const float*)d_in[10]; const float* b4 = (const float*)d_in[11];
    const float* Wc = (const float*)d_in[12]; const float* bc = (const float*)d_in[13];

    const int N = in_sizes[0] / 128;
    const int E = in_sizes[2];
    const int G = out_size;
    const int* src = ei;
    const int* dst = ei + E;

    // workspace carve (re-poisoned to 0xAA every call -> everything read is
    // initialized below)
    char* p = (char*)d_ws;
    auto alloc = [&](size_t bytes) {
        void* q = (void*)p;
        p += (bytes + 255) & ~(size_t)255;
        return q;
    };
    float* deg  = (float*)alloc((size_t)N * 4);
    float* dinv = (float*)alloc((size_t)N * 4);
    int* cnt    = (int*)alloc((size_t)N * 4);
    int* cur    = (int*)alloc((size_t)N * 4);
    int* rowp   = (int*)alloc((size_t)(N + 1) * 4);
    int* bsums  = (int*)alloc(1024 * 4);
    const size_t M = (size_t)E + (size_t)N;
    int* col   = (int*)alloc(M * 4);
    float* val = (float*)alloc(M * 4);
    float* tbuf = (float*)alloc((size_t)N * 128 * 4);
    float* hbuf = (float*)alloc((size_t)N * 128 * 4);
    float* gsum = (float*)alloc((size_t)G * 4);
    float* gcnt = (float*)alloc((size_t)G * 4);

    const int B = 256;
    // --- graph normalization + CSR build ---
    init_nodes<<<(N + B - 1) / B, B, 0, stream>>>(deg, cnt, N);
    init_graphs<<<(G + B - 1) / B, B, 0, stream>>>(gsum, gcnt, G);
    deg_count<<<(E + B - 1) / B, B, 0, stream>>>(dst, ew, deg, cnt, E);
    dinv_k<<<(N + B - 1) / B, B, 0, stream>>>(deg, dinv, N);
    const int total = N + 1;
    const int nb = (total + 1023) / 1024;
    scan1<<<nb, 1024, 0, stream>>>(cnt, rowp, bsums, total, N);
    scan2<<<1, 64, 0, stream>>>(bsums, nb);
    scan3<<<nb, 1024, 0, stream>>>(rowp, bsums, total);
    selfloop_k<<<(N + B - 1) / B, B, 0, stream>>>(rowp, dinv, col, val, cur, N);
    scatter_k<<<(E + B - 1) / B, B, 0, stream>>>(src, dst, ew, dinv, rowp, cur, col, val, E);

    // --- 4 GCN layers: gemm (h@W -> tbuf), aggregate (+bias, relu -> hbuf) ---
    const dim3 ggrid((N + 255) / 256, 4);
    gemm128<<<ggrid, B, 0, stream>>>(x, W1, tbuf, N);
    aggregate<<<N, 64, 0, stream>>>(tbuf, rowp, col, val, b1, hbuf, N);
    gemm128<<<ggrid, B, 0, stream>>>(hbuf, W2, tbuf, N);
    aggregate<<<N, 64, 0, stream>>>(tbuf, rowp, col, val, b2, hbuf, N);
    gemm128<<<ggrid, B, 0, stream>>>(hbuf, W3, tbuf, N);
    aggregate<<<N, 64, 0, stream>>>(tbuf, rowp, col, val, b3, hbuf, N);
    gemm128<<<ggrid, B, 0, stream>>>(hbuf, W4, tbuf, N);
    aggregate<<<N, 64, 0, stream>>>(tbuf, rowp, col, val, b4, hbuf, N);

    // --- mean pool + classifier + sigmoid ---
    pool_k<<<(N + 3) / 4, B, 0, stream>>>(hbuf, batch, Wc, gsum, gcnt, N);
    final_k<<<(G + B - 1) / B, B, 0, stream>>>(gsum, gcnt, bc, (float*)d_out, G);
}

// Round 3
// 1896.565 us; speedup vs baseline: 1.8812x; 1.1110x over previous
//
#include <hip/hip_runtime.h>
#include <math.h>

// ---------------------------------------------------------------------------
// GCN summarizer: 4x (GEMM 128x128 -> normalized-adjacency aggregate + bias
// + relu) -> mean-pool per graph -> dot Wc -> sigmoid.
// R3: CSR build uses ONE packed u64 atomic per edge (count<<40 | fx24(ew));
//     the atomic return value doubles as the edge's slot rank, so the
//     scatter pass needs no atomics at all.
// ---------------------------------------------------------------------------

#define MASK40 ((1ull << 40) - 1)

__global__ void init_packed(unsigned long long* packed, int n) {
    int i = blockIdx.x * blockDim.x + threadIdx.x;
    if (i < n) packed[i] = 0ull;
}

__global__ void init_graphs(float* gsum, float* gcnt, int g) {
    int i = blockIdx.x * blockDim.x + threadIdx.x;
    if (i < g) { gsum[i] = 0.0f; gcnt[i] = 0.0f; }
}

// one u64 atomic per edge: high 24 bits = count, low 40 = sum(ew) in 2^-24 fx.
// returned old value gives this edge's rank among same-dst edges -> slot[e].
__global__ void edge_pass(const int* __restrict__ dst, const float* __restrict__ ew,
                          unsigned long long* packed, int* __restrict__ slot, int E) {
    int e = blockIdx.x * blockDim.x + threadIdx.x;
    if (e < E) {
        int d = dst[e];
        unsigned int fx = (unsigned int)rintf(ew[e] * 16777216.0f);
        unsigned long long old =
            atomicAdd(&packed[d], (1ull << 40) | (unsigned long long)fx);
        slot[e] = (int)(old >> 40);
    }
}

__global__ void dinv_cnt_k(const unsigned long long* __restrict__ packed,
                           float* dinv, int* cnt, int n) {
    int i = blockIdx.x * blockDim.x + threadIdx.x;
    if (i < n) {
        unsigned long long p = packed[i];
        float deg = 1.0f + (float)(p & MASK40) * (1.0f / 16777216.0f);
        dinv[i] = rsqrtf(deg);
        cnt[i] = (int)(p >> 40);
    }
}

// two-level exclusive scan over L[i] = cnt[i]+1 (i<N), 0 otherwise; total N+1
__global__ __launch_bounds__(1024) void scan1(const int* __restrict__ cnt, int* rowp,
                                              int* bsums, int total, int N) {
    __shared__ int sh[1024];
    int i = blockIdx.x * 1024 + threadIdx.x;
    int v = 0;
    if (i < N) v = cnt[i] + 1;
    sh[threadIdx.x] = v;
    __syncthreads();
    for (int off = 1; off < 1024; off <<= 1) {
        int t = (threadIdx.x >= (unsigned)off) ? sh[threadIdx.x - off] : 0;
        __syncthreads();
        sh[threadIdx.x] += t;
        __syncthreads();
    }
    if (i < total) rowp[i] = sh[threadIdx.x] - v;      // exclusive, pre-offset
    if (threadIdx.x == 1023) bsums[blockIdx.x] = sh[1023];
}

__global__ void scan2(int* bsums, int nb) {
    if (threadIdx.x == 0 && blockIdx.x == 0) {
        int run = 0;
        for (int b = 0; b < nb; ++b) { int t = bsums[b]; bsums[b] = run; run += t; }
    }
}

__global__ __launch_bounds__(1024) void scan3(int* rowp, const int* __restrict__ bsums,
                                              int total) {
    int i = blockIdx.x * 1024 + threadIdx.x;
    if (i < total) rowp[i] += bsums[blockIdx.x];
}

__global__ void selfloop_k(const int* __restrict__ rowp, const float* __restrict__ dinv,
                           int* col, float* val, int n) {
    int i = blockIdx.x * blockDim.x + threadIdx.x;
    if (i < n) {
        int p = rowp[i];
        col[p] = i;
        float dv = dinv[i];
        val[p] = dv * dv;        // dinv[i] * 1.0 * dinv[i]
    }
}

// atomic-free scatter: slot[e] precomputed by edge_pass (self loop is slot -1
// i.e. position rowp[d], edges start at rowp[d]+1)
__global__ void scatter2(const int* __restrict__ src, const int* __restrict__ dst,
                         const float* __restrict__ ew, const int* __restrict__ slot,
                         const float* __restrict__ dinv, const int* __restrict__ rowp,
                         int* col, float* val, int E) {
    int e = blockIdx.x * blockDim.x + threadIdx.x;
    if (e < E) {
        int s = src[e], d = dst[e];
        int idx = rowp[d] + 1 + slot[e];
        col[idx] = s;
        val[idx] = dinv[s] * ew[e] * dinv[d];
    }
}

// ---------------------------------------------------------------------------
// GEMM: C[n,128] = A[n,128] @ W[128,128], fp32 vector ALU.
// grid (ceil(n/256), 4). Thread = 1 row x 32 cols (col group = blockIdx.y).
// W indices block-uniform -> s_load + v_fmac with SGPR broadcast. No LDS.
// ---------------------------------------------------------------------------
__global__ __launch_bounds__(256) void gemm128(const float* __restrict__ A,
                                               const float* __restrict__ W,
                                               float* __restrict__ C, int n) {
    const int row = blockIdx.x * 256 + threadIdx.x;
    const int c0 = blockIdx.y * 32;
    if (row >= n) return;

    float acc[32];
#pragma unroll
    for (int j = 0; j < 32; ++j) acc[j] = 0.f;

    const float* Ar = A + (size_t)row * 128;

    for (int kc = 0; kc < 4; ++kc) {
        float4 av[8];
#pragma unroll
        for (int i = 0; i < 8; ++i)
            av[i] = *(const float4*)&Ar[kc * 32 + i * 4];
#pragma unroll
        for (int k4 = 0; k4 < 8; ++k4) {
            const float* Wk = W + (size_t)(kc * 32 + k4 * 4) * 128 + c0;
            const float a0 = av[k4].x, a1 = av[k4].y, a2 = av[k4].z, a3 = av[k4].w;
#pragma unroll
            for (int j = 0; j < 32; ++j) {
                acc[j] = fmaf(a0, Wk[j], acc[j]);
                acc[j] = fmaf(a1, Wk[128 + j], acc[j]);
                acc[j] = fmaf(a2, Wk[256 + j], acc[j]);
                acc[j] = fmaf(a3, Wk[384 + j], acc[j]);
            }
        }
    }

    float* Cr = C + (size_t)row * 128 + c0;   // each thread fills its own 128-B line
#pragma unroll
    for (int j = 0; j < 32; j += 4)
        *(float4*)&Cr[j] = make_float4(acc[j], acc[j + 1], acc[j + 2], acc[j + 3]);
}

// ---------------------------------------------------------------------------
// Aggregate: out[v] = relu( sum_e val[e] * tin[col[e]] + bias ). One node per
// 64-thread block -> rowp/col/val go through s_load; the 512 B/edge feature
// gather is the only vector traffic. Unrolled x4 for MLP.
// ---------------------------------------------------------------------------
__global__ __launch_bounds__(64) void aggregate(const float* __restrict__ tin,
                                                const int* __restrict__ rowp,
                                                const int* __restrict__ col,
                                                const float* __restrict__ val,
                                                const float* __restrict__ bias,
                                                float* __restrict__ out, int n) {
    const int v = blockIdx.x;
    const int lane = threadIdx.x;          // 0..63, feats {2*lane, 2*lane+1}
    const int e0 = rowp[v], e1 = rowp[v + 1];
    float ax = 0.f, ay = 0.f;
    int e = e0;
    for (; e + 4 <= e1; e += 4) {
        const int c0_ = col[e], c1_ = col[e + 1], c2_ = col[e + 2], c3_ = col[e + 3];
        const float w0 = val[e], w1 = val[e + 1], w2 = val[e + 2], w3 = val[e + 3];
        const float2 h0 = *(const float2*)&tin[(size_t)c0_ * 128 + lane * 2];
        const float2 h1 = *(const float2*)&tin[(size_t)c1_ * 128 + lane * 2];
        const float2 h2 = *(const float2*)&tin[(size_t)c2_ * 128 + lane * 2];
        const float2 h3 = *(const float2*)&tin[(size_t)c3_ * 128 + lane * 2];
        ax = fmaf(w0, h0.x, ax); ay = fmaf(w0, h0.y, ay);
        ax = fmaf(w1, h1.x, ax); ay = fmaf(w1, h1.y, ay);
        ax = fmaf(w2, h2.x, ax); ay = fmaf(w2, h2.y, ay);
        ax = fmaf(w3, h3.x, ax); ay = fmaf(w3, h3.y, ay);
    }
    for (; e < e1; ++e) {
        const int c = col[e];
        const float w = val[e];
        const float2 hv = *(const float2*)&tin[(size_t)c * 128 + lane * 2];
        ax = fmaf(w, hv.x, ax); ay = fmaf(w, hv.y, ay);
    }
    const float2 b2 = *(const float2*)&bias[lane * 2];
    float2 r;
    r.x = fmaxf(ax + b2.x, 0.f);
    r.y = fmaxf(ay + b2.y, 0.f);
    *(float2*)&out[(size_t)v * 128 + lane * 2] = r;
}

// per-node scalar s_v = h_v . Wc, atomically segment-summed per graph
__global__ __launch_bounds__(256) void pool_k(const float* __restrict__ h,
                                              const int* __restrict__ batch,
                                              const float* __restrict__ Wc,
                                              float* gsum, float* gcnt, int n) {
    int v = blockIdx.x * 4 + (threadIdx.x >> 6);
    int lane = threadIdx.x & 63;
    if (v >= n) return;
    float2 hv = *(const float2*)&h[(size_t)v * 128 + lane * 2];
    float2 wc = *(const float2*)&Wc[lane * 2];
    float p = hv.x * wc.x + hv.y * wc.y;
#pragma unroll
    for (int off = 32; off; off >>= 1) p += __shfl_down(p, off);
    if (lane == 0) {
        int g = batch[v];
        atomicAdd(&gsum[g], p);
        atomicAdd(&gcnt[g], 1.0f);
    }
}

__global__ void final_k(const float* __restrict__ gsum, const float* __restrict__ gcnt,
                        const float* __restrict__ bc, float* out, int G) {
    int g = blockIdx.x * blockDim.x + threadIdx.x;
    if (g < G) {
        float z = gsum[g] / fmaxf(gcnt[g], 1.0f) + bc[0];
        out[g] = 1.0f / (1.0f + expf(-z));
    }
}

extern "C" void kernel_launch(void* const* d_in, const int* in_sizes, int n_in,
                              void* d_out, int out_size, void* d_ws, size_t ws_size,
                              hipStream_t stream) {
    const float* x   = (const float*)d_in[0];
    const int* ei    = (const int*)d_in[1];
    const float* ew  = (const float*)d_in[2];
    const int* batch = (const int*)d_in[3];
    const float* W1 = (const float*)d_in[4];  const float* b1 = (const float*)d_in[5];
    const float* W2 = (const float*)d_in[6];  const float* b2 = (const float*)d_in[7];
    const float* W3 = (const float*)d_in[8];  const float* b3 = (const float*)d_in[9];
    const float* W4 = (const float*)d_in[10]; const float* b4 = (const float*)d_in[11];
    const float* Wc = (const float*)d_in[12]; const float* bc = (const float*)d_in[13];

    const int N = in_sizes[0] / 128;
    const int E = in_sizes[2];
    const int G = out_size;
    const int* src = ei;
    const int* dst = ei + E;

    // workspace carve (re-poisoned each call; everything read is written below)
    char* p = (char*)d_ws;
    auto alloc = [&](size_t bytes) {
        void* q = (void*)p;
        p += (bytes + 255) & ~(size_t)255;
        return q;
    };
    unsigned long long* packed = (unsigned long long*)alloc((size_t)N * 8);
    float* dinv = (float*)alloc((size_t)N * 4);
    int* cnt    = (int*)alloc((size_t)N * 4);
    int* slot   = (int*)alloc((size_t)E * 4);
    int* rowp   = (int*)alloc((size_t)(N + 1) * 4);
    int* bsums  = (int*)alloc(1024 * 4);
    const size_t M = (size_t)E + (size_t)N;
    int* col   = (int*)alloc(M * 4);
    float* val = (float*)alloc(M * 4);
    float* tbuf = (float*)alloc((size_t)N * 128 * 4);
    float* hbuf = (float*)alloc((size_t)N * 128 * 4);
    float* gsum = (float*)alloc((size_t)G * 4);
    float* gcnt = (float*)alloc((size_t)G * 4);

    const int B = 256;
    // --- graph normalization + CSR build (one atomic per edge total) ---
    init_packed<<<(N + B - 1) / B, B, 0, stream>>>(packed, N);
    init_graphs<<<(G + B - 1) / B, B, 0, stream>>>(gsum, gcnt, G);
    edge_pass<<<(E + B - 1) / B, B, 0, stream>>>(dst, ew, packed, slot, E);
    dinv_cnt_k<<<(N + B - 1) / B, B, 0, stream>>>(packed, dinv, cnt, N);
    const int total = N + 1;
    const int nb = (total + 1023) / 1024;
    scan1<<<nb, 1024, 0, stream>>>(cnt, rowp, bsums, total, N);
    scan2<<<1, 64, 0, stream>>>(bsums, nb);
    scan3<<<nb, 1024, 0, stream>>>(rowp, bsums, total);
    selfloop_k<<<(N + B - 1) / B, B, 0, stream>>>(rowp, dinv, col, val, N);
    scatter2<<<(E + B - 1) / B, B, 0, stream>>>(src, dst, ew, slot, dinv, rowp,
                                                col, val, E);

    // --- 4 GCN layers: gemm (h@W -> tbuf), aggregate (+bias, relu -> hbuf) ---
    const dim3 ggrid((N + 255) / 256, 4);
    gemm128<<<ggrid, B, 0, stream>>>(x, W1, tbuf, N);
    aggregate<<<N, 64, 0, stream>>>(tbuf, rowp, col, val, b1, hbuf, N);
    gemm128<<<ggrid, B, 0, stream>>>(hbuf, W2, tbuf, N);
    aggregate<<<N, 64, 0, stream>>>(tbuf, rowp, col, val, b2, hbuf, N);
    gemm128<<<ggrid, B, 0, stream>>>(hbuf, W3, tbuf, N);
    aggregate<<<N, 64, 0, stream>>>(tbuf, rowp, col, val, b3, hbuf, N);
    gemm128<<<ggrid, B, 0, stream>>>(hbuf, W4, tbuf, N);
    aggregate<<<N, 64, 0, stream>>>(tbuf, rowp, col, val, b4, hbuf, N);

    // --- mean pool + classifier + sigmoid ---
    pool_k<<<(N + 3) / 4, B, 0, stream>>>(hbuf, batch, Wc, gsum, gcnt, N);
    final_k<<<(G + B - 1) / B, B, 0, stream>>>(gsum, gcnt, bc, (float*)d_out, G);
}

// Round 4
// 1634.737 us; speedup vs baseline: 2.1825x; 1.1602x over previous
//
#include <hip/hip_runtime.h>
#include <math.h>

// ---------------------------------------------------------------------------
// GCN summarizer: 4x (GEMM 128x128 -> normalized-adjacency aggregate + bias
// + relu) -> mean-pool per graph -> dot Wc -> sigmoid.
// R4: batch is sorted -> pooling is a segmented sum with ZERO atomics.
//     Classifier dot fused into the 4th aggregate (writes 4 B/node sv instead
//     of 512 B/node h). pool_k/init_graphs/final_k deleted.
// ---------------------------------------------------------------------------

#define MASK40 ((1ull << 40) - 1)

__global__ void init_packed(unsigned long long* packed, int n) {
    int i = blockIdx.x * blockDim.x + threadIdx.x;
    if (i < n) packed[i] = 0ull;
}

// one u64 atomic per edge: high 24 bits = count, low 40 = sum(ew) in 2^-24 fx.
// returned old value gives this edge's rank among same-dst edges -> slot[e].
__global__ void edge_pass(const int* __restrict__ dst, const float* __restrict__ ew,
                          unsigned long long* packed, int* __restrict__ slot, int E) {
    int e = blockIdx.x * blockDim.x + threadIdx.x;
    if (e < E) {
        int d = dst[e];
        unsigned int fx = (unsigned int)rintf(ew[e] * 16777216.0f);
        unsigned long long old =
            atomicAdd(&packed[d], (1ull << 40) | (unsigned long long)fx);
        slot[e] = (int)(old >> 40);
    }
}

__global__ void dinv_cnt_k(const unsigned long long* __restrict__ packed,
                           float* dinv, int* cnt, int n) {
    int i = blockIdx.x * blockDim.x + threadIdx.x;
    if (i < n) {
        unsigned long long p = packed[i];
        float deg = 1.0f + (float)(p & MASK40) * (1.0f / 16777216.0f);
        dinv[i] = rsqrtf(deg);
        cnt[i] = (int)(p >> 40);
    }
}

// two-level exclusive scan over L[i] = cnt[i]+1 (i<N), 0 otherwise; total N+1
__global__ __launch_bounds__(1024) void scan1(const int* __restrict__ cnt, int* rowp,
                                              int* bsums, int total, int N) {
    __shared__ int sh[1024];
    int i = blockIdx.x * 1024 + threadIdx.x;
    int v = 0;
    if (i < N) v = cnt[i] + 1;
    sh[threadIdx.x] = v;
    __syncthreads();
    for (int off = 1; off < 1024; off <<= 1) {
        int t = (threadIdx.x >= (unsigned)off) ? sh[threadIdx.x - off] : 0;
        __syncthreads();
        sh[threadIdx.x] += t;
        __syncthreads();
    }
    if (i < total) rowp[i] = sh[threadIdx.x] - v;      // exclusive, pre-offset
    if (threadIdx.x == 1023) bsums[blockIdx.x] = sh[1023];
}

__global__ void scan2(int* bsums, int nb) {
    if (threadIdx.x == 0 && blockIdx.x == 0) {
        int run = 0;
        for (int b = 0; b < nb; ++b) { int t = bsums[b]; bsums[b] = run; run += t; }
    }
}

__global__ __launch_bounds__(1024) void scan3(int* rowp, const int* __restrict__ bsums,
                                              int total) {
    int i = blockIdx.x * 1024 + threadIdx.x;
    if (i < total) rowp[i] += bsums[blockIdx.x];
}

__global__ void selfloop_k(const int* __restrict__ rowp, const float* __restrict__ dinv,
                           int* col, float* val, int n) {
    int i = blockIdx.x * blockDim.x + threadIdx.x;
    if (i < n) {
        int p = rowp[i];
        col[p] = i;
        float dv = dinv[i];
        val[p] = dv * dv;        // dinv[i] * 1.0 * dinv[i]
    }
}

// atomic-free scatter: slot[e] precomputed by edge_pass (self loop occupies
// rowp[d]; edges start at rowp[d]+1)
__global__ void scatter2(const int* __restrict__ src, const int* __restrict__ dst,
                         const float* __restrict__ ew, const int* __restrict__ slot,
                         const float* __restrict__ dinv, const int* __restrict__ rowp,
                         int* col, float* val, int E) {
    int e = blockIdx.x * blockDim.x + threadIdx.x;
    if (e < E) {
        int s = src[e], d = dst[e];
        int idx = rowp[d] + 1 + slot[e];
        col[idx] = s;
        val[idx] = dinv[s] * ew[e] * dinv[d];
    }
}

// ---------------------------------------------------------------------------
// GEMM: C[n,128] = A[n,128] @ W[128,128], fp32 vector ALU.
// grid (ceil(n/256), 4). Thread = 1 row x 32 cols (col group = blockIdx.y).
// W indices block-uniform -> s_load + v_fmac with SGPR broadcast. No LDS.
// ---------------------------------------------------------------------------
__global__ __launch_bounds__(256) void gemm128(const float* __restrict__ A,
                                               const float* __restrict__ W,
                                               float* __restrict__ C, int n) {
    const int row = blockIdx.x * 256 + threadIdx.x;
    const int c0 = blockIdx.y * 32;
    if (row >= n) return;

    float acc[32];
#pragma unroll
    for (int j = 0; j < 32; ++j) acc[j] = 0.f;

    const float* Ar = A + (size_t)row * 128;

    for (int kc = 0; kc < 4; ++kc) {
        float4 av[8];
#pragma unroll
        for (int i = 0; i < 8; ++i)
            av[i] = *(const float4*)&Ar[kc * 32 + i * 4];
#pragma unroll
        for (int k4 = 0; k4 < 8; ++k4) {
            const float* Wk = W + (size_t)(kc * 32 + k4 * 4) * 128 + c0;
            const float a0 = av[k4].x, a1 = av[k4].y, a2 = av[k4].z, a3 = av[k4].w;
#pragma unroll
            for (int j = 0; j < 32; ++j) {
                acc[j] = fmaf(a0, Wk[j], acc[j]);
                acc[j] = fmaf(a1, Wk[128 + j], acc[j]);
                acc[j] = fmaf(a2, Wk[256 + j], acc[j]);
                acc[j] = fmaf(a3, Wk[384 + j], acc[j]);
            }
        }
    }

    float* Cr = C + (size_t)row * 128 + c0;   // each thread fills its own 128-B line
#pragma unroll
    for (int j = 0; j < 32; j += 4)
        *(float4*)&Cr[j] = make_float4(acc[j], acc[j + 1], acc[j + 2], acc[j + 3]);
}

// ---------------------------------------------------------------------------
// Aggregate: out[v] = relu( sum_e val[e] * tin[col[e]] + bias ). One node per
// 64-thread block -> rowp/col/val go through s_load; the 512 B/edge feature
// gather is the only vector traffic. Unrolled x4 for MLP.
// ---------------------------------------------------------------------------
__global__ __launch_bounds__(64) void aggregate(const float* __restrict__ tin,
                                                const int* __restrict__ rowp,
                                                const int* __restrict__ col,
                                                const float* __restrict__ val,
                                                const float* __restrict__ bias,
                                                float* __restrict__ out, int n) {
    const int v = blockIdx.x;
    const int lane = threadIdx.x;          // 0..63, feats {2*lane, 2*lane+1}
    const int e0 = rowp[v], e1 = rowp[v + 1];
    float ax = 0.f, ay = 0.f;
    int e = e0;
    for (; e + 4 <= e1; e += 4) {
        const int c0_ = col[e], c1_ = col[e + 1], c2_ = col[e + 2], c3_ = col[e + 3];
        const float w0 = val[e], w1 = val[e + 1], w2 = val[e + 2], w3 = val[e + 3];
        const float2 h0 = *(const float2*)&tin[(size_t)c0_ * 128 + lane * 2];
        const float2 h1 = *(const float2*)&tin[(size_t)c1_ * 128 + lane * 2];
        const float2 h2 = *(const float2*)&tin[(size_t)c2_ * 128 + lane * 2];
        const float2 h3 = *(const float2*)&tin[(size_t)c3_ * 128 + lane * 2];
        ax = fmaf(w0, h0.x, ax); ay = fmaf(w0, h0.y, ay);
        ax = fmaf(w1, h1.x, ax); ay = fmaf(w1, h1.y, ay);
        ax = fmaf(w2, h2.x, ax); ay = fmaf(w2, h2.y, ay);
        ax = fmaf(w3, h3.x, ax); ay = fmaf(w3, h3.y, ay);
    }
    for (; e < e1; ++e) {
        const int c = col[e];
        const float w = val[e];
        const float2 hv = *(const float2*)&tin[(size_t)c * 128 + lane * 2];
        ax = fmaf(w, hv.x, ax); ay = fmaf(w, hv.y, ay);
    }
    const float2 b2 = *(const float2*)&bias[lane * 2];
    float2 r;
    r.x = fmaxf(ax + b2.x, 0.f);
    r.y = fmaxf(ay + b2.y, 0.f);
    *(float2*)&out[(size_t)v * 128 + lane * 2] = r;
}

// last layer: same gather, but h_v never materialized — dot with Wc, wave
// reduce, write sv[v] (4 B/node).
__global__ __launch_bounds__(64) void aggregate_last(const float* __restrict__ tin,
                                                     const int* __restrict__ rowp,
                                                     const int* __restrict__ col,
                                                     const float* __restrict__ val,
                                                     const float* __restrict__ bias,
                                                     const float* __restrict__ Wc,
                                                     float* __restrict__ sv, int n) {
    const int v = blockIdx.x;
    const int lane = threadIdx.x;
    const int e0 = rowp[v], e1 = rowp[v + 1];
    float ax = 0.f, ay = 0.f;
    int e = e0;
    for (; e + 4 <= e1; e += 4) {
        const int c0_ = col[e], c1_ = col[e + 1], c2_ = col[e + 2], c3_ = col[e + 3];
        const float w0 = val[e], w1 = val[e + 1], w2 = val[e + 2], w3 = val[e + 3];
        const float2 h0 = *(const float2*)&tin[(size_t)c0_ * 128 + lane * 2];
        const float2 h1 = *(const float2*)&tin[(size_t)c1_ * 128 + lane * 2];
        const float2 h2 = *(const float2*)&tin[(size_t)c2_ * 128 + lane * 2];
        const float2 h3 = *(const float2*)&tin[(size_t)c3_ * 128 + lane * 2];
        ax = fmaf(w0, h0.x, ax); ay = fmaf(w0, h0.y, ay);
        ax = fmaf(w1, h1.x, ax); ay = fmaf(w1, h1.y, ay);
        ax = fmaf(w2, h2.x, ax); ay = fmaf(w2, h2.y, ay);
        ax = fmaf(w3, h3.x, ax); ay = fmaf(w3, h3.y, ay);
    }
    for (; e < e1; ++e) {
        const int c = col[e];
        const float w = val[e];
        const float2 hv = *(const float2*)&tin[(size_t)c * 128 + lane * 2];
        ax = fmaf(w, hv.x, ax); ay = fmaf(w, hv.y, ay);
    }
    const float2 b2 = *(const float2*)&bias[lane * 2];
    const float2 wc = *(const float2*)&Wc[lane * 2];
    float p = fmaxf(ax + b2.x, 0.f) * wc.x + fmaxf(ay + b2.y, 0.f) * wc.y;
#pragma unroll
    for (int off = 32; off; off >>= 1) p += __shfl_down(p, off);
    if (lane == 0) sv[v] = p;
}

// start[g] = lower_bound(batch, g) for g in [0, G]; batch is sorted.
__global__ void gstart_k(const int* __restrict__ batch, int* start, int N, int G) {
    int g = blockIdx.x * blockDim.x + threadIdx.x;
    if (g <= G) {
        int lo = 0, hi = N;
        while (lo < hi) {
            int mid = (lo + hi) >> 1;
            if (batch[mid] < g) lo = mid + 1; else hi = mid;
        }
        start[g] = lo;
    }
}

// one block per graph: mean of sv over the (contiguous) segment, sigmoid.
__global__ __launch_bounds__(256) void seg_pool(const float* __restrict__ sv,
                                                const int* __restrict__ start,
                                                const float* __restrict__ bc,
                                                float* __restrict__ out, int G) {
    __shared__ float sh[4];
    const int g = blockIdx.x;
    const int s = start[g], epos = start[g + 1];
    float acc = 0.f;
    for (int i = s + threadIdx.x; i < epos; i += 256) acc += sv[i];
#pragma unroll
    for (int off = 32; off; off >>= 1) acc += __shfl_down(acc, off);
    if ((threadIdx.x & 63) == 0) sh[threadIdx.x >> 6] = acc;
    __syncthreads();
    if (threadIdx.x == 0) {
        float sum = sh[0] + sh[1] + sh[2] + sh[3];
        float cnt = (float)(epos - s);
        float z = sum / fmaxf(cnt, 1.0f) + bc[0];
        out[g] = 1.0f / (1.0f + expf(-z));
    }
}

extern "C" void kernel_launch(void* const* d_in, const int* in_sizes, int n_in,
                              void* d_out, int out_size, void* d_ws, size_t ws_size,
                              hipStream_t stream) {
    const float* x   = (const float*)d_in[0];
    const int* ei    = (const int*)d_in[1];
    const float* ew  = (const float*)d_in[2];
    const int* batch = (const int*)d_in[3];
    const float* W1 = (const float*)d_in[4];  const float* b1 = (const float*)d_in[5];
    const float* W2 = (const float*)d_in[6];  const float* b2 = (const float*)d_in[7];
    const float* W3 = (const float*)d_in[8];  const float* b3 = (const float*)d_in[9];
    const float* W4 = (const float*)d_in[10]; const float* b4 = (const float*)d_in[11];
    const float* Wc = (const float*)d_in[12]; const float* bc = (const float*)d_in[13];

    const int N = in_sizes[0] / 128;
    const int E = in_sizes[2];
    const int G = out_size;
    const int* src = ei;
    const int* dst = ei + E;

    // workspace carve (re-poisoned each call; everything read is written below)
    char* p = (char*)d_ws;
    auto alloc = [&](size_t bytes) {
        void* q = (void*)p;
        p += (bytes + 255) & ~(size_t)255;
        return q;
    };
    unsigned long long* packed = (unsigned long long*)alloc((size_t)N * 8);
    float* dinv = (float*)alloc((size_t)N * 4);
    int* cnt    = (int*)alloc((size_t)N * 4);
    int* slot   = (int*)alloc((size_t)E * 4);
    int* rowp   = (int*)alloc((size_t)(N + 1) * 4);
    int* bsums  = (int*)alloc(1024 * 4);
    const size_t M = (size_t)E + (size_t)N;
    int* col   = (int*)alloc(M * 4);
    float* val = (float*)alloc(M * 4);
    float* tbuf = (float*)alloc((size_t)N * 128 * 4);
    float* hbuf = (float*)alloc((size_t)N * 128 * 4);
    float* sv   = (float*)alloc((size_t)N * 4);
    int* start  = (int*)alloc((size_t)(G + 1) * 4);

    const int B = 256;
    // --- graph normalization + CSR build (one atomic per edge total) ---
    init_packed<<<(N + B - 1) / B, B, 0, stream>>>(packed, N);
    edge_pass<<<(E + B - 1) / B, B, 0, stream>>>(dst, ew, packed, slot, E);
    dinv_cnt_k<<<(N + B - 1) / B, B, 0, stream>>>(packed, dinv, cnt, N);
    const int total = N + 1;
    const int nb = (total + 1023) / 1024;
    scan1<<<nb, 1024, 0, stream>>>(cnt, rowp, bsums, total, N);
    scan2<<<1, 64, 0, stream>>>(bsums, nb);
    scan3<<<nb, 1024, 0, stream>>>(rowp, bsums, total);
    selfloop_k<<<(N + B - 1) / B, B, 0, stream>>>(rowp, dinv, col, val, N);
    scatter2<<<(E + B - 1) / B, B, 0, stream>>>(src, dst, ew, slot, dinv, rowp,
                                                col, val, E);
    gstart_k<<<(G + 1 + B - 1) / B, B, 0, stream>>>(batch, start, N, G);

    // --- 4 GCN layers ---
    const dim3 ggrid((N + 255) / 256, 4);
    gemm128<<<ggrid, B, 0, stream>>>(x, W1, tbuf, N);
    aggregate<<<N, 64, 0, stream>>>(tbuf, rowp, col, val, b1, hbuf, N);
    gemm128<<<ggrid, B, 0, stream>>>(hbuf, W2, tbuf, N);
    aggregate<<<N, 64, 0, stream>>>(tbuf, rowp, col, val, b2, hbuf, N);
    gemm128<<<ggrid, B, 0, stream>>>(hbuf, W3, tbuf, N);
    aggregate<<<N, 64, 0, stream>>>(tbuf, rowp, col, val, b3, hbuf, N);
    gemm128<<<ggrid, B, 0, stream>>>(hbuf, W4, tbuf, N);
    aggregate_last<<<N, 64, 0, stream>>>(tbuf, rowp, col, val, b4, Wc, sv, N);

    // --- segmented mean pool (batch sorted) + sigmoid ---
    seg_pool<<<G, B, 0, stream>>>(sv, start, bc, (float*)d_out, G);
}

// Round 5
// 1236.767 us; speedup vs baseline: 2.8848x; 1.3218x over previous
//
#include <hip/hip_runtime.h>
#include <math.h>

// ---------------------------------------------------------------------------
// GCN summarizer: 4x (GEMM 128x128 -> normalized-adjacency aggregate + bias
// + relu) -> segmented mean-pool -> dot Wc -> sigmoid.
// R5: GEMM output (the gather operand) stored as packed bf16 -> the random
//     per-edge gather moves 256 B/node-row instead of 512. fp32 accumulate;
//     one bf16 rounding per layer.
// ---------------------------------------------------------------------------

#define MASK40 ((1ull << 40) - 1)

__device__ inline unsigned f2bf(float x) {            // round-to-nearest-even
    unsigned u = __float_as_uint(x);
    return (u + 0x7FFFu + ((u >> 16) & 1u)) >> 16;
}
__device__ inline float2 bf2_unpack(unsigned u) {     // {low=even feat, high=odd}
    float2 r;
    r.x = __uint_as_float(u << 16);
    r.y = __uint_as_float(u & 0xFFFF0000u);
    return r;
}

__global__ void init_packed(unsigned long long* packed, int n) {
    int i = blockIdx.x * blockDim.x + threadIdx.x;
    if (i < n) packed[i] = 0ull;
}

// one u64 atomic per edge: high 24 bits = count, low 40 = sum(ew) in 2^-24 fx.
// returned old value gives this edge's rank among same-dst edges -> slot[e].
__global__ void edge_pass(const int* __restrict__ dst, const float* __restrict__ ew,
                          unsigned long long* packed, int* __restrict__ slot, int E) {
    int e = blockIdx.x * blockDim.x + threadIdx.x;
    if (e < E) {
        int d = dst[e];
        unsigned int fx = (unsigned int)rintf(ew[e] * 16777216.0f);
        unsigned long long old =
            atomicAdd(&packed[d], (1ull << 40) | (unsigned long long)fx);
        slot[e] = (int)(old >> 40);
    }
}

__global__ void dinv_cnt_k(const unsigned long long* __restrict__ packed,
                           float* dinv, int* cnt, int n) {
    int i = blockIdx.x * blockDim.x + threadIdx.x;
    if (i < n) {
        unsigned long long p = packed[i];
        float deg = 1.0f + (float)(p & MASK40) * (1.0f / 16777216.0f);
        dinv[i] = rsqrtf(deg);
        cnt[i] = (int)(p >> 40);
    }
}

// two-level exclusive scan over L[i] = cnt[i]+1 (i<N), 0 otherwise; total N+1
__global__ __launch_bounds__(1024) void scan1(const int* __restrict__ cnt, int* rowp,
                                              int* bsums, int total, int N) {
    __shared__ int sh[1024];
    int i = blockIdx.x * 1024 + threadIdx.x;
    int v = 0;
    if (i < N) v = cnt[i] + 1;
    sh[threadIdx.x] = v;
    __syncthreads();
    for (int off = 1; off < 1024; off <<= 1) {
        int t = (threadIdx.x >= (unsigned)off) ? sh[threadIdx.x - off] : 0;
        __syncthreads();
        sh[threadIdx.x] += t;
        __syncthreads();
    }
    if (i < total) rowp[i] = sh[threadIdx.x] - v;      // exclusive, pre-offset
    if (threadIdx.x == 1023) bsums[blockIdx.x] = sh[1023];
}

__global__ void scan2(int* bsums, int nb) {
    if (threadIdx.x == 0 && blockIdx.x == 0) {
        int run = 0;
        for (int b = 0; b < nb; ++b) { int t = bsums[b]; bsums[b] = run; run += t; }
    }
}

__global__ __launch_bounds__(1024) void scan3(int* rowp, const int* __restrict__ bsums,
                                              int total) {
    int i = blockIdx.x * 1024 + threadIdx.x;
    if (i < total) rowp[i] += bsums[blockIdx.x];
}

__global__ void selfloop_k(const int* __restrict__ rowp, const float* __restrict__ dinv,
                           int* col, float* val, int n) {
    int i = blockIdx.x * blockDim.x + threadIdx.x;
    if (i < n) {
        int p = rowp[i];
        col[p] = i;
        float dv = dinv[i];
        val[p] = dv * dv;        // dinv[i] * 1.0 * dinv[i]
    }
}

// atomic-free scatter: slot[e] precomputed by edge_pass (self loop occupies
// rowp[d]; edges start at rowp[d]+1)
__global__ void scatter2(const int* __restrict__ src, const int* __restrict__ dst,
                         const float* __restrict__ ew, const int* __restrict__ slot,
                         const float* __restrict__ dinv, const int* __restrict__ rowp,
                         int* col, float* val, int E) {
    int e = blockIdx.x * blockDim.x + threadIdx.x;
    if (e < E) {
        int s = src[e], d = dst[e];
        int idx = rowp[d] + 1 + slot[e];
        col[idx] = s;
        val[idx] = dinv[s] * ew[e] * dinv[d];
    }
}

// ---------------------------------------------------------------------------
// GEMM: C[n,128] = A[n,128] @ W[128,128]; A fp32, C packed bf16 (2 feats/uint).
// grid (ceil(n/256), 4). Thread = 1 row x 32 cols. W via SGPR broadcast.
// ---------------------------------------------------------------------------
__global__ __launch_bounds__(256) void gemm128(const float* __restrict__ A,
                                               const float* __restrict__ W,
                                               unsigned* __restrict__ C, int n) {
    const int row = blockIdx.x * 256 + threadIdx.x;
    const int c0 = blockIdx.y * 32;
    if (row >= n) return;

    float acc[32];
#pragma unroll
    for (int j = 0; j < 32; ++j) acc[j] = 0.f;

    const float* Ar = A + (size_t)row * 128;

    for (int kc = 0; kc < 4; ++kc) {
        float4 av[8];
#pragma unroll
        for (int i = 0; i < 8; ++i)
            av[i] = *(const float4*)&Ar[kc * 32 + i * 4];
#pragma unroll
        for (int k4 = 0; k4 < 8; ++k4) {
            const float* Wk = W + (size_t)(kc * 32 + k4 * 4) * 128 + c0;
            const float a0 = av[k4].x, a1 = av[k4].y, a2 = av[k4].z, a3 = av[k4].w;
#pragma unroll
            for (int j = 0; j < 32; ++j) {
                acc[j] = fmaf(a0, Wk[j], acc[j]);
                acc[j] = fmaf(a1, Wk[128 + j], acc[j]);
                acc[j] = fmaf(a2, Wk[256 + j], acc[j]);
                acc[j] = fmaf(a3, Wk[384 + j], acc[j]);
            }
        }
    }

    // pack 32 cols -> 16 uints (feat 2k low, 2k+1 high); row = 64 uints
    unsigned* Cr = C + (size_t)row * 64 + (c0 >> 1);
#pragma unroll
    for (int i = 0; i < 4; ++i) {
        uint4 w;
        w.x = f2bf(acc[i * 8 + 0]) | (f2bf(acc[i * 8 + 1]) << 16);
        w.y = f2bf(acc[i * 8 + 2]) | (f2bf(acc[i * 8 + 3]) << 16);
        w.z = f2bf(acc[i * 8 + 4]) | (f2bf(acc[i * 8 + 5]) << 16);
        w.w = f2bf(acc[i * 8 + 6]) | (f2bf(acc[i * 8 + 7]) << 16);
        *(uint4*)&Cr[i * 4] = w;
    }
}

// ---------------------------------------------------------------------------
// Aggregate: out[v] = relu( sum_e val[e] * tin[col[e]] + bias ). tin is packed
// bf16 (64 uints/row) -> 256 B/edge gather, 1 dword/lane. fp32 accumulate.
// One node per 64-thread block; rowp/col/val via s_load. Unrolled x4.
// ---------------------------------------------------------------------------
__global__ __launch_bounds__(64) void aggregate(const unsigned* __restrict__ tin,
                                                const int* __restrict__ rowp,
                                                const int* __restrict__ col,
                                                const float* __restrict__ val,
                                                const float* __restrict__ bias,
                                                float* __restrict__ out, int n) {
    const int v = blockIdx.x;
    const int lane = threadIdx.x;          // 0..63, feats {2*lane, 2*lane+1}
    const int e0 = rowp[v], e1 = rowp[v + 1];
    float ax = 0.f, ay = 0.f;
    int e = e0;
    for (; e + 4 <= e1; e += 4) {
        const int c0_ = col[e], c1_ = col[e + 1], c2_ = col[e + 2], c3_ = col[e + 3];
        const float w0 = val[e], w1 = val[e + 1], w2 = val[e + 2], w3 = val[e + 3];
        const unsigned u0 = tin[(size_t)c0_ * 64 + lane];
        const unsigned u1 = tin[(size_t)c1_ * 64 + lane];
        const unsigned u2 = tin[(size_t)c2_ * 64 + lane];
        const unsigned u3 = tin[(size_t)c3_ * 64 + lane];
        const float2 h0 = bf2_unpack(u0), h1 = bf2_unpack(u1);
        const float2 h2 = bf2_unpack(u2), h3 = bf2_unpack(u3);
        ax = fmaf(w0, h0.x, ax); ay = fmaf(w0, h0.y, ay);
        ax = fmaf(w1, h1.x, ax); ay = fmaf(w1, h1.y, ay);
        ax = fmaf(w2, h2.x, ax); ay = fmaf(w2, h2.y, ay);
        ax = fmaf(w3, h3.x, ax); ay = fmaf(w3, h3.y, ay);
    }
    for (; e < e1; ++e) {
        const float2 hv = bf2_unpack(tin[(size_t)col[e] * 64 + lane]);
        const float w = val[e];
        ax = fmaf(w, hv.x, ax); ay = fmaf(w, hv.y, ay);
    }
    const float2 b2 = *(const float2*)&bias[lane * 2];
    float2 r;
    r.x = fmaxf(ax + b2.x, 0.f);
    r.y = fmaxf(ay + b2.y, 0.f);
    *(float2*)&out[(size_t)v * 128 + lane * 2] = r;
}

// last layer: gather as above, then dot with Wc + wave reduce -> sv[v] (4 B).
__global__ __launch_bounds__(64) void aggregate_last(const unsigned* __restrict__ tin,
                                                     const int* __restrict__ rowp,
                                                     const int* __restrict__ col,
                                                     const float* __restrict__ val,
                                                     const float* __restrict__ bias,
                                                     const float* __restrict__ Wc,
                                                     float* __restrict__ sv, int n) {
    const int v = blockIdx.x;
    const int lane = threadIdx.x;
    const int e0 = rowp[v], e1 = rowp[v + 1];
    float ax = 0.f, ay = 0.f;
    int e = e0;
    for (; e + 4 <= e1; e += 4) {
        const int c0_ = col[e], c1_ = col[e + 1], c2_ = col[e + 2], c3_ = col[e + 3];
        const float w0 = val[e], w1 = val[e + 1], w2 = val[e + 2], w3 = val[e + 3];
        const float2 h0 = bf2_unpack(tin[(size_t)c0_ * 64 + lane]);
        const float2 h1 = bf2_unpack(tin[(size_t)c1_ * 64 + lane]);
        const float2 h2 = bf2_unpack(tin[(size_t)c2_ * 64 + lane]);
        const float2 h3 = bf2_unpack(tin[(size_t)c3_ * 64 + lane]);
        ax = fmaf(w0, h0.x, ax); ay = fmaf(w0, h0.y, ay);
        ax = fmaf(w1, h1.x, ax); ay = fmaf(w1, h1.y, ay);
        ax = fmaf(w2, h2.x, ax); ay = fmaf(w2, h2.y, ay);
        ax = fmaf(w3, h3.x, ax); ay = fmaf(w3, h3.y, ay);
    }
    for (; e < e1; ++e) {
        const float2 hv = bf2_unpack(tin[(size_t)col[e] * 64 + lane]);
        const float w = val[e];
        ax = fmaf(w, hv.x, ax); ay = fmaf(w, hv.y, ay);
    }
    const float2 b2 = *(const float2*)&bias[lane * 2];
    const float2 wc = *(const float2*)&Wc[lane * 2];
    float p = fmaxf(ax + b2.x, 0.f) * wc.x + fmaxf(ay + b2.y, 0.f) * wc.y;
#pragma unroll
    for (int off = 32; off; off >>= 1) p += __shfl_down(p, off);
    if (lane == 0) sv[v] = p;
}

// start[g] = lower_bound(batch, g) for g in [0, G]; batch is sorted.
__global__ void gstart_k(const int* __restrict__ batch, int* start, int N, int G) {
    int g = blockIdx.x * blockDim.x + threadIdx.x;
    if (g <= G) {
        int lo = 0, hi = N;
        while (lo < hi) {
            int mid = (lo + hi) >> 1;
            if (batch[mid] < g) lo = mid + 1; else hi = mid;
        }
        start[g] = lo;
    }
}

// one block per graph: mean of sv over the (contiguous) segment, sigmoid.
__global__ __launch_bounds__(256) void seg_pool(const float* __restrict__ sv,
                                                const int* __restrict__ start,
                                                const float* __restrict__ bc,
                                                float* __restrict__ out, int G) {
    __shared__ float sh[4];
    const int g = blockIdx.x;
    const int s = start[g], epos = start[g + 1];
    float acc = 0.f;
    for (int i = s + threadIdx.x; i < epos; i += 256) acc += sv[i];
#pragma unroll
    for (int off = 32; off; off >>= 1) acc += __shfl_down(acc, off);
    if ((threadIdx.x & 63) == 0) sh[threadIdx.x >> 6] = acc;
    __syncthreads();
    if (threadIdx.x == 0) {
        float sum = sh[0] + sh[1] + sh[2] + sh[3];
        float cnt = (float)(epos - s);
        float z = sum / fmaxf(cnt, 1.0f) + bc[0];
        out[g] = 1.0f / (1.0f + expf(-z));
    }
}

extern "C" void kernel_launch(void* const* d_in, const int* in_sizes, int n_in,
                              void* d_out, int out_size, void* d_ws, size_t ws_size,
                              hipStream_t stream) {
    const float* x   = (const float*)d_in[0];
    const int* ei    = (const int*)d_in[1];
    const float* ew  = (const float*)d_in[2];
    const int* batch = (const int*)d_in[3];
    const float* W1 = (const float*)d_in[4];  const float* b1 = (const float*)d_in[5];
    const float* W2 = (const float*)d_in[6];  const float* b2 = (const float*)d_in[7];
    const float* W3 = (const float*)d_in[8];  const float* b3 = (const float*)d_in[9];
    const float* W4 = (const float*)d_in[10]; const float* b4 = (const float*)d_in[11];
    const float* Wc = (const float*)d_in[12]; const float* bc = (const float*)d_in[13];

    const int N = in_sizes[0] / 128;
    const int E = in_sizes[2];
    const int G = out_size;
    const int* src = ei;
    const int* dst = ei + E;

    // workspace carve (re-poisoned each call; everything read is written below)
    char* p = (char*)d_ws;
    auto alloc = [&](size_t bytes) {
        void* q = (void*)p;
        p += (bytes + 255) & ~(size_t)255;
        return q;
    };
    unsigned long long* packed = (unsigned long long*)alloc((size_t)N * 8);
    float* dinv = (float*)alloc((size_t)N * 4);
    int* cnt    = (int*)alloc((size_t)N * 4);
    int* slot   = (int*)alloc((size_t)E * 4);
    int* rowp   = (int*)alloc((size_t)(N + 1) * 4);
    int* bsums  = (int*)alloc(1024 * 4);
    const size_t M = (size_t)E + (size_t)N;
    int* col   = (int*)alloc(M * 4);
    float* val = (float*)alloc(M * 4);
    unsigned* tbuf = (unsigned*)alloc((size_t)N * 64 * 4);   // bf16-packed GEMM out
    float* hbuf = (float*)alloc((size_t)N * 128 * 4);
    float* sv   = (float*)alloc((size_t)N * 4);
    int* start  = (int*)alloc((size_t)(G + 1) * 4);

    const int B = 256;
    // --- graph normalization + CSR build (one atomic per edge total) ---
    init_packed<<<(N + B - 1) / B, B, 0, stream>>>(packed, N);
    edge_pass<<<(E + B - 1) / B, B, 0, stream>>>(dst, ew, packed, slot, E);
    dinv_cnt_k<<<(N + B - 1) / B, B, 0, stream>>>(packed, dinv, cnt, N);
    const int total = N + 1;
    const int nb = (total + 1023) / 1024;
    scan1<<<nb, 1024, 0, stream>>>(cnt, rowp, bsums, total, N);
    scan2<<<1, 64, 0, stream>>>(bsums, nb);
    scan3<<<nb, 1024, 0, stream>>>(rowp, bsums, total);
    selfloop_k<<<(N + B - 1) / B, B, 0, stream>>>(rowp, dinv, col, val, N);
    scatter2<<<(E + B - 1) / B, B, 0, stream>>>(src, dst, ew, slot, dinv, rowp,
                                                col, val, E);
    gstart_k<<<(G + 1 + B - 1) / B, B, 0, stream>>>(batch, start, N, G);

    // --- 4 GCN layers ---
    const dim3 ggrid((N + 255) / 256, 4);
    gemm128<<<ggrid, B, 0, stream>>>(x, W1, tbuf, N);
    aggregate<<<N, 64, 0, stream>>>(tbuf, rowp, col, val, b1, hbuf, N);
    gemm128<<<ggrid, B, 0, stream>>>(hbuf, W2, tbuf, N);
    aggregate<<<N, 64, 0, stream>>>(tbuf, rowp, col, val, b2, hbuf, N);
    gemm128<<<ggrid, B, 0, stream>>>(hbuf, W3, tbuf, N);
    aggregate<<<N, 64, 0, stream>>>(tbuf, rowp, col, val, b3, hbuf, N);
    gemm128<<<ggrid, B, 0, stream>>>(hbuf, W4, tbuf, N);
    aggregate_last<<<N, 64, 0, stream>>>(tbuf, rowp, col, val, b4, Wc, sv, N);

    // --- segmented mean pool (batch sorted) + sigmoid ---
    seg_pool<<<G, B, 0, stream>>>(sv, start, bc, (float*)d_out, G);
}

// Round 6
// 1206.359 us; speedup vs baseline: 2.9576x; 1.0252x over previous
//
#include <hip/hip_runtime.h>
#include <math.h>

// ---------------------------------------------------------------------------
// GCN summarizer: 4x (GEMM 128x128 -> normalized-adjacency aggregate + bias
// + relu) -> segmented mean-pool -> dot Wc -> sigmoid.
// R6: CSR payload interleaved as int2{col, val} -> scatter writes ONE random
//     8-B sector per edge instead of two; slot stream narrowed to u16.
// ---------------------------------------------------------------------------

#define MASK40 ((1ull << 40) - 1)

__device__ inline unsigned f2bf(float x) {            // round-to-nearest-even
    unsigned u = __float_as_uint(x);
    return (u + 0x7FFFu + ((u >> 16) & 1u)) >> 16;
}
__device__ inline float2 bf2_unpack(unsigned u) {     // {low=even feat, high=odd}
    float2 r;
    r.x = __uint_as_float(u << 16);
    r.y = __uint_as_float(u & 0xFFFF0000u);
    return r;
}

__global__ void init_packed(unsigned long long* packed, int n) {
    int i = blockIdx.x * blockDim.x + threadIdx.x;
    if (i < n) packed[i] = 0ull;
}

// one u64 atomic per edge: high 24 bits = count, low 40 = sum(ew) in 2^-24 fx.
// returned old value gives this edge's rank among same-dst edges -> slot[e].
__global__ void edge_pass(const int* __restrict__ dst, const float* __restrict__ ew,
                          unsigned long long* packed, unsigned short* __restrict__ slot,
                          int E) {
    int e = blockIdx.x * blockDim.x + threadIdx.x;
    if (e < E) {
        int d = dst[e];
        unsigned int fx = (unsigned int)rintf(ew[e] * 16777216.0f);
        unsigned long long old =
            atomicAdd(&packed[d], (1ull << 40) | (unsigned long long)fx);
        slot[e] = (unsigned short)(old >> 40);
    }
}

__global__ void dinv_cnt_k(const unsigned long long* __restrict__ packed,
                           float* dinv, int* cnt, int n) {
    int i = blockIdx.x * blockDim.x + threadIdx.x;
    if (i < n) {
        unsigned long long p = packed[i];
        float deg = 1.0f + (float)(p & MASK40) * (1.0f / 16777216.0f);
        dinv[i] = rsqrtf(deg);
        cnt[i] = (int)(p >> 40);
    }
}

// two-level exclusive scan over L[i] = cnt[i]+1 (i<N), 0 otherwise; total N+1
__global__ __launch_bounds__(1024) void scan1(const int* __restrict__ cnt, int* rowp,
                                              int* bsums, int total, int N) {
    __shared__ int sh[1024];
    int i = blockIdx.x * 1024 + threadIdx.x;
    int v = 0;
    if (i < N) v = cnt[i] + 1;
    sh[threadIdx.x] = v;
    __syncthreads();
    for (int off = 1; off < 1024; off <<= 1) {
        int t = (threadIdx.x >= (unsigned)off) ? sh[threadIdx.x - off] : 0;
        __syncthreads();
        sh[threadIdx.x] += t;
        __syncthreads();
    }
    if (i < total) rowp[i] = sh[threadIdx.x] - v;      // exclusive, pre-offset
    if (threadIdx.x == 1023) bsums[blockIdx.x] = sh[1023];
}

__global__ void scan2(int* bsums, int nb) {
    if (threadIdx.x == 0 && blockIdx.x == 0) {
        int run = 0;
        for (int b = 0; b < nb; ++b) { int t = bsums[b]; bsums[b] = run; run += t; }
    }
}

__global__ __launch_bounds__(1024) void scan3(int* rowp, const int* __restrict__ bsums,
                                              int total) {
    int i = blockIdx.x * 1024 + threadIdx.x;
    if (i < total) rowp[i] += bsums[blockIdx.x];
}

__global__ void selfloop_k(const int* __restrict__ rowp, const float* __restrict__ dinv,
                           int2* colval, int n) {
    int i = blockIdx.x * blockDim.x + threadIdx.x;
    if (i < n) {
        float dv = dinv[i];
        int2 cv;
        cv.x = i;
        cv.y = __float_as_int(dv * dv);   // dinv[i] * 1.0 * dinv[i]
        colval[rowp[i]] = cv;
    }
}

// atomic-free scatter: one 8-B write per edge (col+val interleaved).
__global__ void scatter2(const int* __restrict__ src, const int* __restrict__ dst,
                         const float* __restrict__ ew,
                         const unsigned short* __restrict__ slot,
                         const float* __restrict__ dinv, const int* __restrict__ rowp,
                         int2* colval, int E) {
    int e = blockIdx.x * blockDim.x + threadIdx.x;
    if (e < E) {
        int s = src[e], d = dst[e];
        int idx = rowp[d] + 1 + (int)slot[e];
        int2 cv;
        cv.x = s;
        cv.y = __float_as_int(dinv[s] * ew[e] * dinv[d]);
        colval[idx] = cv;
    }
}

// ---------------------------------------------------------------------------
// GEMM: C[n,128] = A[n,128] @ W[128,128]; A fp32, C packed bf16 (2 feats/uint).
// grid (ceil(n/256), 4). Thread = 1 row x 32 cols. W via SGPR broadcast.
// ---------------------------------------------------------------------------
__global__ __launch_bounds__(256) void gemm128(const float* __restrict__ A,
                                               const float* __restrict__ W,
                                               unsigned* __restrict__ C, int n) {
    const int row = blockIdx.x * 256 + threadIdx.x;
    const int c0 = blockIdx.y * 32;
    if (row >= n) return;

    float acc[32];
#pragma unroll
    for (int j = 0; j < 32; ++j) acc[j] = 0.f;

    const float* Ar = A + (size_t)row * 128;

    for (int kc = 0; kc < 4; ++kc) {
        float4 av[8];
#pragma unroll
        for (int i = 0; i < 8; ++i)
            av[i] = *(const float4*)&Ar[kc * 32 + i * 4];
#pragma unroll
        for (int k4 = 0; k4 < 8; ++k4) {
            const float* Wk = W + (size_t)(kc * 32 + k4 * 4) * 128 + c0;
            const float a0 = av[k4].x, a1 = av[k4].y, a2 = av[k4].z, a3 = av[k4].w;
#pragma unroll
            for (int j = 0; j < 32; ++j) {
                acc[j] = fmaf(a0, Wk[j], acc[j]);
                acc[j] = fmaf(a1, Wk[128 + j], acc[j]);
                acc[j] = fmaf(a2, Wk[256 + j], acc[j]);
                acc[j] = fmaf(a3, Wk[384 + j], acc[j]);
            }
        }
    }

    // pack 32 cols -> 16 uints (feat 2k low, 2k+1 high); row = 64 uints
    unsigned* Cr = C + (size_t)row * 64 + (c0 >> 1);
#pragma unroll
    for (int i = 0; i < 4; ++i) {
        uint4 w;
        w.x = f2bf(acc[i * 8 + 0]) | (f2bf(acc[i * 8 + 1]) << 16);
        w.y = f2bf(acc[i * 8 + 2]) | (f2bf(acc[i * 8 + 3]) << 16);
        w.z = f2bf(acc[i * 8 + 4]) | (f2bf(acc[i * 8 + 5]) << 16);
        w.w = f2bf(acc[i * 8 + 6]) | (f2bf(acc[i * 8 + 7]) << 16);
        *(uint4*)&Cr[i * 4] = w;
    }
}

// ---------------------------------------------------------------------------
// Aggregate: out[v] = relu( sum_e val*tin[col] + bias ). tin packed bf16 (64
// uints/row) -> 256 B/edge gather, 1 dword/lane. One node per 64-thread
// block; rowp/colval via s_load. Unrolled x4.
// ---------------------------------------------------------------------------
__global__ __launch_bounds__(64) void aggregate(const unsigned* __restrict__ tin,
                                                const int* __restrict__ rowp,
                                                const int2* __restrict__ colval,
                                                const float* __restrict__ bias,
                                                float* __restrict__ out, int n) {
    const int v = blockIdx.x;
    const int lane = threadIdx.x;          // 0..63, feats {2*lane, 2*lane+1}
    const int e0 = rowp[v], e1 = rowp[v + 1];
    float ax = 0.f, ay = 0.f;
    int e = e0;
    for (; e + 4 <= e1; e += 4) {
        const int2 cv0 = colval[e],     cv1 = colval[e + 1];
        const int2 cv2 = colval[e + 2], cv3 = colval[e + 3];
        const unsigned u0 = tin[(size_t)cv0.x * 64 + lane];
        const unsigned u1 = tin[(size_t)cv1.x * 64 + lane];
        const unsigned u2 = tin[(size_t)cv2.x * 64 + lane];
        const unsigned u3 = tin[(size_t)cv3.x * 64 + lane];
        const float w0 = __int_as_float(cv0.y), w1 = __int_as_float(cv1.y);
        const float w2 = __int_as_float(cv2.y), w3 = __int_as_float(cv3.y);
        const float2 h0 = bf2_unpack(u0), h1 = bf2_unpack(u1);
        const float2 h2 = bf2_unpack(u2), h3 = bf2_unpack(u3);
        ax = fmaf(w0, h0.x, ax); ay = fmaf(w0, h0.y, ay);
        ax = fmaf(w1, h1.x, ax); ay = fmaf(w1, h1.y, ay);
        ax = fmaf(w2, h2.x, ax); ay = fmaf(w2, h2.y, ay);
        ax = fmaf(w3, h3.x, ax); ay = fmaf(w3, h3.y, ay);
    }
    for (; e < e1; ++e) {
        const int2 cv = colval[e];
        const float2 hv = bf2_unpack(tin[(size_t)cv.x * 64 + lane]);
        const float w = __int_as_float(cv.y);
        ax = fmaf(w, hv.x, ax); ay = fmaf(w, hv.y, ay);
    }
    const float2 b2 = *(const float2*)&bias[lane * 2];
    float2 r;
    r.x = fmaxf(ax + b2.x, 0.f);
    r.y = fmaxf(ay + b2.y, 0.f);
    *(float2*)&out[(size_t)v * 128 + lane * 2] = r;
}

// last layer: gather as above, then dot with Wc + wave reduce -> sv[v] (4 B).
__global__ __launch_bounds__(64) void aggregate_last(const unsigned* __restrict__ tin,
                                                     const int* __restrict__ rowp,
                                                     const int2* __restrict__ colval,
                                                     const float* __restrict__ bias,
                                                     const float* __restrict__ Wc,
                                                     float* __restrict__ sv, int n) {
    const int v = blockIdx.x;
    const int lane = threadIdx.x;
    const int e0 = rowp[v], e1 = rowp[v + 1];
    float ax = 0.f, ay = 0.f;
    int e = e0;
    for (; e + 4 <= e1; e += 4) {
        const int2 cv0 = colval[e],     cv1 = colval[e + 1];
        const int2 cv2 = colval[e + 2], cv3 = colval[e + 3];
        const float2 h0 = bf2_unpack(tin[(size_t)cv0.x * 64 + lane]);
        const float2 h1 = bf2_unpack(tin[(size_t)cv1.x * 64 + lane]);
        const float2 h2 = bf2_unpack(tin[(size_t)cv2.x * 64 + lane]);
        const float2 h3 = bf2_unpack(tin[(size_t)cv3.x * 64 + lane]);
        const float w0 = __int_as_float(cv0.y), w1 = __int_as_float(cv1.y);
        const float w2 = __int_as_float(cv2.y), w3 = __int_as_float(cv3.y);
        ax = fmaf(w0, h0.x, ax); ay = fmaf(w0, h0.y, ay);
        ax = fmaf(w1, h1.x, ax); ay = fmaf(w1, h1.y, ay);
        ax = fmaf(w2, h2.x, ax); ay = fmaf(w2, h2.y, ay);
        ax = fmaf(w3, h3.x, ax); ay = fmaf(w3, h3.y, ay);
    }
    for (; e < e1; ++e) {
        const int2 cv = colval[e];
        const float2 hv = bf2_unpack(tin[(size_t)cv.x * 64 + lane]);
        const float w = __int_as_float(cv.y);
        ax = fmaf(w, hv.x, ax); ay = fmaf(w, hv.y, ay);
    }
    const float2 b2 = *(const float2*)&bias[lane * 2];
    const float2 wc = *(const float2*)&Wc[lane * 2];
    float p = fmaxf(ax + b2.x, 0.f) * wc.x + fmaxf(ay + b2.y, 0.f) * wc.y;
#pragma unroll
    for (int off = 32; off; off >>= 1) p += __shfl_down(p, off);
    if (lane == 0) sv[v] = p;
}

// start[g] = lower_bound(batch, g) for g in [0, G]; batch is sorted.
__global__ void gstart_k(const int* __restrict__ batch, int* start, int N, int G) {
    int g = blockIdx.x * blockDim.x + threadIdx.x;
    if (g <= G) {
        int lo = 0, hi = N;
        while (lo < hi) {
            int mid = (lo + hi) >> 1;
            if (batch[mid] < g) lo = mid + 1; else hi = mid;
        }
        start[g] = lo;
    }
}

// one block per graph: mean of sv over the (contiguous) segment, sigmoid.
__global__ __launch_bounds__(256) void seg_pool(const float* __restrict__ sv,
                                                const int* __restrict__ start,
                                                const float* __restrict__ bc,
                                                float* __restrict__ out, int G) {
    __shared__ float sh[4];
    const int g = blockIdx.x;
    const int s = start[g], epos = start[g + 1];
    float acc = 0.f;
    for (int i = s + threadIdx.x; i < epos; i += 256) acc += sv[i];
#pragma unroll
    for (int off = 32; off; off >>= 1) acc += __shfl_down(acc, off);
    if ((threadIdx.x & 63) == 0) sh[threadIdx.x >> 6] = acc;
    __syncthreads();
    if (threadIdx.x == 0) {
        float sum = sh[0] + sh[1] + sh[2] + sh[3];
        float cnt = (float)(epos - s);
        float z = sum / fmaxf(cnt, 1.0f) + bc[0];
        out[g] = 1.0f / (1.0f + expf(-z));
    }
}

extern "C" void kernel_launch(void* const* d_in, const int* in_sizes, int n_in,
                              void* d_out, int out_size, void* d_ws, size_t ws_size,
                              hipStream_t stream) {
    const float* x   = (const float*)d_in[0];
    const int* ei    = (const int*)d_in[1];
    const float* ew  = (const float*)d_in[2];
    const int* batch = (const int*)d_in[3];
    const float* W1 = (const float*)d_in[4];  const float* b1 = (const float*)d_in[5];
    const float* W2 = (const float*)d_in[6];  const float* b2 = (const float*)d_in[7];
    const float* W3 = (const float*)d_in[8];  const float* b3 = (const float*)d_in[9];
    const float* W4 = (const float*)d_in[10]; const float* b4 = (const float*)d_in[11];
    const float* Wc = (const float*)d_in[12]; const float* bc = (const float*)d_in[13];

    const int N = in_sizes[0] / 128;
    const int E = in_sizes[2];
    const int G = out_size;
    const int* src = ei;
    const int* dst = ei + E;

    // workspace carve (re-poisoned each call; everything read is written below)
    char* p = (char*)d_ws;
    auto alloc = [&](size_t bytes) {
        void* q = (void*)p;
        p += (bytes + 255) & ~(size_t)255;
        return q;
    };
    unsigned long long* packed = (unsigned long long*)alloc((size_t)N * 8);
    float* dinv = (float*)alloc((size_t)N * 4);
    int* cnt    = (int*)alloc((size_t)N * 4);
    unsigned short* slot = (unsigned short*)alloc((size_t)E * 2);
    int* rowp   = (int*)alloc((size_t)(N + 1) * 4);
    int* bsums  = (int*)alloc(1024 * 4);
    const size_t M = (size_t)E + (size_t)N;
    int2* colval = (int2*)alloc(M * 8);
    unsigned* tbuf = (unsigned*)alloc((size_t)N * 64 * 4);   // bf16-packed GEMM out
    float* hbuf = (float*)alloc((size_t)N * 128 * 4);
    float* sv   = (float*)alloc((size_t)N * 4);
    int* start  = (int*)alloc((size_t)(G + 1) * 4);

    const int B = 256;
    // --- graph normalization + CSR build (one atomic per edge total) ---
    init_packed<<<(N + B - 1) / B, B, 0, stream>>>(packed, N);
    edge_pass<<<(E + B - 1) / B, B, 0, stream>>>(dst, ew, packed, slot, E);
    dinv_cnt_k<<<(N + B - 1) / B, B, 0, stream>>>(packed, dinv, cnt, N);
    const int total = N + 1;
    const int nb = (total + 1023) / 1024;
    scan1<<<nb, 1024, 0, stream>>>(cnt, rowp, bsums, total, N);
    scan2<<<1, 64, 0, stream>>>(bsums, nb);
    scan3<<<nb, 1024, 0, stream>>>(rowp, bsums, total);
    selfloop_k<<<(N + B - 1) / B, B, 0, stream>>>(rowp, dinv, colval, N);
    scatter2<<<(E + B - 1) / B, B, 0, stream>>>(src, dst, ew, slot, dinv, rowp,
                                                colval, E);
    gstart_k<<<(G + 1 + B - 1) / B, B, 0, stream>>>(batch, start, N, G);

    // --- 4 GCN layers ---
    const dim3 ggrid((N + 255) / 256, 4);
    gemm128<<<ggrid, B, 0, stream>>>(x, W1, tbuf, N);
    aggregate<<<N, 64, 0, stream>>>(tbuf, rowp, colval, b1, hbuf, N);
    gemm128<<<ggrid, B, 0, stream>>>(hbuf, W2, tbuf, N);
    aggregate<<<N, 64, 0, stream>>>(tbuf, rowp, colval, b2, hbuf, N);
    gemm128<<<ggrid, B, 0, stream>>>(hbuf, W3, tbuf, N);
    aggregate<<<N, 64, 0, stream>>>(tbuf, rowp, colval, b3, hbuf, N);
    gemm128<<<ggrid, B, 0, stream>>>(hbuf, W4, tbuf, N);
    aggregate_last<<<N, 64, 0, stream>>>(tbuf, rowp, colval, b4, Wc, sv, N);

    // --- segmented mean pool (batch sorted) + sigmoid ---
    seg_pool<<<G, B, 0, stream>>>(sv, start, bc, (float*)d_out, G);
}

// Round 7
// 959.918 us; speedup vs baseline: 3.7169x; 1.2567x over previous
//
#include <hip/hip_runtime.h>
#include <math.h>

// ---------------------------------------------------------------------------
// GCN summarizer: 4x (GEMM 128x128 -> normalized-adjacency aggregate + bias
// + relu) -> segmented mean-pool -> dot Wc -> sigmoid.
// R7: gather operand (tbuf) stored as OCP fp8-e4m3 (128 B/edge gather, HW
//     cvt pack/unpack); layer activations (hbuf) stored as packed bf16.
//     fp32 accumulation everywhere.
// ---------------------------------------------------------------------------

#define MASK40 ((1ull << 40) - 1)

typedef float v2f __attribute__((ext_vector_type(2)));

__device__ inline unsigned f2bf(float x) {            // round-to-nearest-even
    unsigned u = __float_as_uint(x);
    return (u + 0x7FFFu + ((u >> 16) & 1u)) >> 16;
}

__global__ void init_packed(unsigned long long* packed, int n) {
    int i = blockIdx.x * blockDim.x + threadIdx.x;
    if (i < n) packed[i] = 0ull;
}

// one u64 atomic per edge: high 24 bits = count, low 40 = sum(ew) in 2^-24 fx.
// returned old value gives this edge's rank among same-dst edges -> slot[e].
__global__ void edge_pass(const int* __restrict__ dst, const float* __restrict__ ew,
                          unsigned long long* packed, unsigned short* __restrict__ slot,
                          int E) {
    int e = blockIdx.x * blockDim.x + threadIdx.x;
    if (e < E) {
        int d = dst[e];
        unsigned int fx = (unsigned int)rintf(ew[e] * 16777216.0f);
        unsigned long long old =
            atomicAdd(&packed[d], (1ull << 40) | (unsigned long long)fx);
        slot[e] = (unsigned short)(old >> 40);
    }
}

__global__ void dinv_cnt_k(const unsigned long long* __restrict__ packed,
                           float* dinv, int* cnt, int n) {
    int i = blockIdx.x * blockDim.x + threadIdx.x;
    if (i < n) {
        unsigned long long p = packed[i];
        float deg = 1.0f + (float)(p & MASK40) * (1.0f / 16777216.0f);
        dinv[i] = rsqrtf(deg);
        cnt[i] = (int)(p >> 40);
    }
}

// two-level exclusive scan over L[i] = cnt[i]+1 (i<N), 0 otherwise; total N+1
__global__ __launch_bounds__(1024) void scan1(const int* __restrict__ cnt, int* rowp,
                                              int* bsums, int total, int N) {
    __shared__ int sh[1024];
    int i = blockIdx.x * 1024 + threadIdx.x;
    int v = 0;
    if (i < N) v = cnt[i] + 1;
    sh[threadIdx.x] = v;
    __syncthreads();
    for (int off = 1; off < 1024; off <<= 1) {
        int t = (threadIdx.x >= (unsigned)off) ? sh[threadIdx.x - off] : 0;
        __syncthreads();
        sh[threadIdx.x] += t;
        __syncthreads();
    }
    if (i < total) rowp[i] = sh[threadIdx.x] - v;      // exclusive, pre-offset
    if (threadIdx.x == 1023) bsums[blockIdx.x] = sh[1023];
}

__global__ void scan2(int* bsums, int nb) {
    if (threadIdx.x == 0 && blockIdx.x == 0) {
        int run = 0;
        for (int b = 0; b < nb; ++b) { int t = bsums[b]; bsums[b] = run; run += t; }
    }
}

__global__ __launch_bounds__(1024) void scan3(int* rowp, const int* __restrict__ bsums,
                                              int total) {
    int i = blockIdx.x * 1024 + threadIdx.x;
    if (i < total) rowp[i] += bsums[blockIdx.x];
}

__global__ void selfloop_k(const int* __restrict__ rowp, const float* __restrict__ dinv,
                           int2* colval, int n) {
    int i = blockIdx.x * blockDim.x + threadIdx.x;
    if (i < n) {
        float dv = dinv[i];
        int2 cv;
        cv.x = i;
        cv.y = __float_as_int(dv * dv);   // dinv[i] * 1.0 * dinv[i]
        colval[rowp[i]] = cv;
    }
}

// atomic-free scatter: one 8-B write per edge (col+val interleaved).
__global__ void scatter2(const int* __restrict__ src, const int* __restrict__ dst,
                         const float* __restrict__ ew,
                         const unsigned short* __restrict__ slot,
                         const float* __restrict__ dinv, const int* __restrict__ rowp,
                         int2* colval, int E) {
    int e = blockIdx.x * blockDim.x + threadIdx.x;
    if (e < E) {
        int s = src[e], d = dst[e];
        int idx = rowp[d] + 1 + (int)slot[e];
        int2 cv;
        cv.x = s;
        cv.y = __float_as_int(dinv[s] * ew[e] * dinv[d]);
        colval[idx] = cv;
    }
}

// ---------------------------------------------------------------------------
// GEMM: C[n,128] = A[n,128] @ W[128,128]; A fp32 (layer 1) or packed bf16
// (layers 2-4); C packed fp8 e4m3 (4 feats/uint, 32 uints/row).
// grid (ceil(n/256), 4). Thread = 1 row x 32 cols. W via SGPR broadcast.
// ---------------------------------------------------------------------------
template <int BF16IN>
__global__ __launch_bounds__(256) void gemm128(const void* __restrict__ Av,
                                               const float* __restrict__ W,
                                               unsigned* __restrict__ C, int n) {
    const int row = blockIdx.x * 256 + threadIdx.x;
    const int c0 = blockIdx.y * 32;
    if (row >= n) return;

    float acc[32];
#pragma unroll
    for (int j = 0; j < 32; ++j) acc[j] = 0.f;

    for (int kc = 0; kc < 4; ++kc) {
        float a[32];
        if (BF16IN) {
            const unsigned* Ar = (const unsigned*)Av + (size_t)row * 64 + kc * 16;
#pragma unroll
            for (int i = 0; i < 4; ++i) {
                uint4 u = *(const uint4*)&Ar[i * 4];
                a[i * 8 + 0] = __uint_as_float(u.x << 16);
                a[i * 8 + 1] = __uint_as_float(u.x & 0xFFFF0000u);
                a[i * 8 + 2] = __uint_as_float(u.y << 16);
                a[i * 8 + 3] = __uint_as_float(u.y & 0xFFFF0000u);
                a[i * 8 + 4] = __uint_as_float(u.z << 16);
                a[i * 8 + 5] = __uint_as_float(u.z & 0xFFFF0000u);
                a[i * 8 + 6] = __uint_as_float(u.w << 16);
                a[i * 8 + 7] = __uint_as_float(u.w & 0xFFFF0000u);
            }
        } else {
            const float* Ar = (const float*)Av + (size_t)row * 128 + kc * 32;
#pragma unroll
            for (int i = 0; i < 8; ++i) {
                float4 f = *(const float4*)&Ar[i * 4];
                a[i * 4 + 0] = f.x; a[i * 4 + 1] = f.y;
                a[i * 4 + 2] = f.z; a[i * 4 + 3] = f.w;
            }
        }
#pragma unroll
        for (int k4 = 0; k4 < 8; ++k4) {
            const float* Wk = W + (size_t)(kc * 32 + k4 * 4) * 128 + c0;
            const float a0 = a[k4 * 4 + 0], a1 = a[k4 * 4 + 1];
            const float a2 = a[k4 * 4 + 2], a3 = a[k4 * 4 + 3];
#pragma unroll
            for (int j = 0; j < 32; ++j) {
                acc[j] = fmaf(a0, Wk[j], acc[j]);
                acc[j] = fmaf(a1, Wk[128 + j], acc[j]);
                acc[j] = fmaf(a2, Wk[256 + j], acc[j]);
                acc[j] = fmaf(a3, Wk[384 + j], acc[j]);
            }
        }
    }

    // pack 32 cols -> 8 dwords of fp8 e4m3 (byte k of dword i = feat 4i+k)
    unsigned* Cr = C + (size_t)row * 32 + blockIdx.y * 8;
#pragma unroll
    for (int i = 0; i < 2; ++i) {
        uint4 w;
        int d0 = __builtin_amdgcn_cvt_pk_fp8_f32(acc[i*16+ 0], acc[i*16+ 1], 0, false);
        d0     = __builtin_amdgcn_cvt_pk_fp8_f32(acc[i*16+ 2], acc[i*16+ 3], d0, true);
        int d1 = __builtin_amdgcn_cvt_pk_fp8_f32(acc[i*16+ 4], acc[i*16+ 5], 0, false);
        d1     = __builtin_amdgcn_cvt_pk_fp8_f32(acc[i*16+ 6], acc[i*16+ 7], d1, true);
        int d2 = __builtin_amdgcn_cvt_pk_fp8_f32(acc[i*16+ 8], acc[i*16+ 9], 0, false);
        d2     = __builtin_amdgcn_cvt_pk_fp8_f32(acc[i*16+10], acc[i*16+11], d2, true);
        int d3 = __builtin_amdgcn_cvt_pk_fp8_f32(acc[i*16+12], acc[i*16+13], 0, false);
        d3     = __builtin_amdgcn_cvt_pk_fp8_f32(acc[i*16+14], acc[i*16+15], d3, true);
        w.x = (unsigned)d0; w.y = (unsigned)d1; w.z = (unsigned)d2; w.w = (unsigned)d3;
        *(uint4*)&Cr[i * 4] = w;
    }
}

// ---------------------------------------------------------------------------
// Aggregate: out[v] = relu( sum_e val*tin[col] + bias ). tin packed fp8
// (128 B/row) -> one ushort/lane per edge; HW cvt to f32; fp32 accumulate.
// Writes packed-bf16 activations. One node per 64-thread block.
// ---------------------------------------------------------------------------
__global__ __launch_bounds__(64) void aggregate(const unsigned short* __restrict__ t8,
                                                const int* __restrict__ rowp,
                                                const int2* __restrict__ colval,
                                                const float* __restrict__ bias,
                                                unsigned* __restrict__ out16, int n) {
    const int v = blockIdx.x;
    const int lane = threadIdx.x;          // 0..63, feats {2*lane, 2*lane+1}
    const int e0 = rowp[v], e1 = rowp[v + 1];
    float ax = 0.f, ay = 0.f;
    int e = e0;
    for (; e + 4 <= e1; e += 4) {
        const int2 cv0 = colval[e],     cv1 = colval[e + 1];
        const int2 cv2 = colval[e + 2], cv3 = colval[e + 3];
        const unsigned short u0 = t8[(size_t)cv0.x * 64 + lane];
        const unsigned short u1 = t8[(size_t)cv1.x * 64 + lane];
        const unsigned short u2 = t8[(size_t)cv2.x * 64 + lane];
        const unsigned short u3 = t8[(size_t)cv3.x * 64 + lane];
        const float w0 = __int_as_float(cv0.y), w1 = __int_as_float(cv1.y);
        const float w2 = __int_as_float(cv2.y), w3 = __int_as_float(cv3.y);
        const v2f h0 = __builtin_amdgcn_cvt_pk_f32_fp8((int)u0, false);
        const v2f h1 = __builtin_amdgcn_cvt_pk_f32_fp8((int)u1, false);
        const v2f h2 = __builtin_amdgcn_cvt_pk_f32_fp8((int)u2, false);
        const v2f h3 = __builtin_amdgcn_cvt_pk_f32_fp8((int)u3, false);
        ax = fmaf(w0, h0.x, ax); ay = fmaf(w0, h0.y, ay);
        ax = fmaf(w1, h1.x, ax); ay = fmaf(w1, h1.y, ay);
        ax = fmaf(w2, h2.x, ax); ay = fmaf(w2, h2.y, ay);
        ax = fmaf(w3, h3.x, ax); ay = fmaf(w3, h3.y, ay);
    }
    for (; e < e1; ++e) {
        const int2 cv = colval[e];
        const v2f hv = __builtin_amdgcn_cvt_pk_f32_fp8(
            (int)t8[(size_t)cv.x * 64 + lane], false);
        const float w = __int_as_float(cv.y);
        ax = fmaf(w, hv.x, ax); ay = fmaf(w, hv.y, ay);
    }
    const float2 b2 = *(const float2*)&bias[lane * 2];
    const float rx = fmaxf(ax + b2.x, 0.f);
    const float ry = fmaxf(ay + b2.y, 0.f);
    out16[(size_t)v * 64 + lane] = f2bf(rx) | (f2bf(ry) << 16);
}

// last layer: gather as above, then dot with Wc + wave reduce -> sv[v] (4 B).
__global__ __launch_bounds__(64) void aggregate_last(const unsigned short* __restrict__ t8,
                                                     const int* __restrict__ rowp,
                                                     const int2* __restrict__ colval,
                                                     const float* __restrict__ bias,
                                                     const float* __restrict__ Wc,
                                                     float* __restrict__ sv, int n) {
    const int v = blockIdx.x;
    const int lane = threadIdx.x;
    const int e0 = rowp[v], e1 = rowp[v + 1];
    float ax = 0.f, ay = 0.f;
    int e = e0;
    for (; e + 4 <= e1; e += 4) {
        const int2 cv0 = colval[e],     cv1 = colval[e + 1];
        const int2 cv2 = colval[e + 2], cv3 = colval[e + 3];
        const unsigned short u0 = t8[(size_t)cv0.x * 64 + lane];
        const unsigned short u1 = t8[(size_t)cv1.x * 64 + lane];
        const unsigned short u2 = t8[(size_t)cv2.x * 64 + lane];
        const unsigned short u3 = t8[(size_t)cv3.x * 64 + lane];
        const float w0 = __int_as_float(cv0.y), w1 = __int_as_float(cv1.y);
        const float w2 = __int_as_float(cv2.y), w3 = __int_as_float(cv3.y);
        const v2f h0 = __builtin_amdgcn_cvt_pk_f32_fp8((int)u0, false);
        const v2f h1 = __builtin_amdgcn_cvt_pk_f32_fp8((int)u1, false);
        const v2f h2 = __builtin_amdgcn_cvt_pk_f32_fp8((int)u2, false);
        const v2f h3 = __builtin_amdgcn_cvt_pk_f32_fp8((int)u3, false);
        ax = fmaf(w0, h0.x, ax); ay = fmaf(w0, h0.y, ay);
        ax = fmaf(w1, h1.x, ax); ay = fmaf(w1, h1.y, ay);
        ax = fmaf(w2, h2.x, ax); ay = fmaf(w2, h2.y, ay);
        ax = fmaf(w3, h3.x, ax); ay = fmaf(w3, h3.y, ay);
    }
    for (; e < e1; ++e) {
        const int2 cv = colval[e];
        const v2f hv = __builtin_amdgcn_cvt_pk_f32_fp8(
            (int)t8[(size_t)cv.x * 64 + lane], false);
        const float w = __int_as_float(cv.y);
        ax = fmaf(w, hv.x, ax); ay = fmaf(w, hv.y, ay);
    }
    const float2 b2 = *(const float2*)&bias[lane * 2];
    const float2 wc = *(const float2*)&Wc[lane * 2];
    float p = fmaxf(ax + b2.x, 0.f) * wc.x + fmaxf(ay + b2.y, 0.f) * wc.y;
#pragma unroll
    for (int off = 32; off; off >>= 1) p += __shfl_down(p, off);
    if (lane == 0) sv[v] = p;
}

// start[g] = lower_bound(batch, g) for g in [0, G]; batch is sorted.
__global__ void gstart_k(const int* __restrict__ batch, int* start, int N, int G) {
    int g = blockIdx.x * blockDim.x + threadIdx.x;
    if (g <= G) {
        int lo = 0, hi = N;
        while (lo < hi) {
            int mid = (lo + hi) >> 1;
            if (batch[mid] < g) lo = mid + 1; else hi = mid;
        }
        start[g] = lo;
    }
}

// one block per graph: mean of sv over the (contiguous) segment, sigmoid.
__global__ __launch_bounds__(256) void seg_pool(const float* __restrict__ sv,
                                                const int* __restrict__ start,
                                                const float* __restrict__ bc,
                                                float* __restrict__ out, int G) {
    __shared__ float sh[4];
    const int g = blockIdx.x;
    const int s = start[g], epos = start[g + 1];
    float acc = 0.f;
    for (int i = s + threadIdx.x; i < epos; i += 256) acc += sv[i];
#pragma unroll
    for (int off = 32; off; off >>= 1) acc += __shfl_down(acc, off);
    if ((threadIdx.x & 63) == 0) sh[threadIdx.x >> 6] = acc;
    __syncthreads();
    if (threadIdx.x == 0) {
        float sum = sh[0] + sh[1] + sh[2] + sh[3];
        float cnt = (float)(epos - s);
        float z = sum / fmaxf(cnt, 1.0f) + bc[0];
        out[g] = 1.0f / (1.0f + expf(-z));
    }
}

extern "C" void kernel_launch(void* const* d_in, const int* in_sizes, int n_in,
                              void* d_out, int out_size, void* d_ws, size_t ws_size,
                              hipStream_t stream) {
    const float* x   = (const float*)d_in[0];
    const int* ei    = (const int*)d_in[1];
    const float* ew  = (const float*)d_in[2];
    const int* batch = (const int*)d_in[3];
    const float* W1 = (const float*)d_in[4];  const float* b1 = (const float*)d_in[5];
    const float* W2 = (const float*)d_in[6];  const float* b2 = (const float*)d_in[7];
    const float* W3 = (const float*)d_in[8];  const float* b3 = (const float*)d_in[9];
    const float* W4 = (const float*)d_in[10]; const float* b4 = (const float*)d_in[11];
    const float* Wc = (const float*)d_in[12]; const float* bc = (const float*)d_in[13];

    const int N = in_sizes[0] / 128;
    const int E = in_sizes[2];
    const int G = out_size;
    const int* src = ei;
    const int* dst = ei + E;

    // workspace carve (re-poisoned each call; everything read is written below)
    char* p = (char*)d_ws;
    auto alloc = [&](size_t bytes) {
        void* q = (void*)p;
        p += (bytes + 255) & ~(size_t)255;
        return q;
    };
    unsigned long long* packed = (unsigned long long*)alloc((size_t)N * 8);
    float* dinv = (float*)alloc((size_t)N * 4);
    int* cnt    = (int*)alloc((size_t)N * 4);
    unsigned short* slot = (unsigned short*)alloc((size_t)E * 2);
    int* rowp   = (int*)alloc((size_t)(N + 1) * 4);
    int* bsums  = (int*)alloc(1024 * 4);
    const size_t M = (size_t)E + (size_t)N;
    int2* colval = (int2*)alloc(M * 8);
    unsigned* tbuf = (unsigned*)alloc((size_t)N * 32 * 4);   // fp8-packed GEMM out
    unsigned* hbuf = (unsigned*)alloc((size_t)N * 64 * 4);   // bf16-packed activations
    float* sv   = (float*)alloc((size_t)N * 4);
    int* start  = (int*)alloc((size_t)(G + 1) * 4);

    const int B = 256;
    // --- graph normalization + CSR build (one atomic per edge total) ---
    init_packed<<<(N + B - 1) / B, B, 0, stream>>>(packed, N);
    edge_pass<<<(E + B - 1) / B, B, 0, stream>>>(dst, ew, packed, slot, E);
    dinv_cnt_k<<<(N + B - 1) / B, B, 0, stream>>>(packed, dinv, cnt, N);
    const int total = N + 1;
    const int nb = (total + 1023) / 1024;
    scan1<<<nb, 1024, 0, stream>>>(cnt, rowp, bsums, total, N);
    scan2<<<1, 64, 0, stream>>>(bsums, nb);
    scan3<<<nb, 1024, 0, stream>>>(rowp, bsums, total);
    selfloop_k<<<(N + B - 1) / B, B, 0, stream>>>(rowp, dinv, colval, N);
    scatter2<<<(E + B - 1) / B, B, 0, stream>>>(src, dst, ew, slot, dinv, rowp,
                                                colval, E);
    gstart_k<<<(G + 1 + B - 1) / B, B, 0, stream>>>(batch, start, N, G);

    // --- 4 GCN layers ---
    const dim3 ggrid((N + 255) / 256, 4);
    const unsigned short* t8 = (const unsigned short*)tbuf;
    gemm128<0><<<ggrid, B, 0, stream>>>(x, W1, tbuf, N);
    aggregate<<<N, 64, 0, stream>>>(t8, rowp, colval, b1, hbuf, N);
    gemm128<1><<<ggrid, B, 0, stream>>>(hbuf, W2, tbuf, N);
    aggregate<<<N, 64, 0, stream>>>(t8, rowp, colval, b2, hbuf, N);
    gemm128<1><<<ggrid, B, 0, stream>>>(hbuf, W3, tbuf, N);
    aggregate<<<N, 64, 0, stream>>>(t8, rowp, colval, b3, hbuf, N);
    gemm128<1><<<ggrid, B, 0, stream>>>(hbuf, W4, tbuf, N);
    aggregate_last<<<N, 64, 0, stream>>>(t8, rowp, colval, b4, Wc, sv, N);

    // --- segmented mean pool (batch sorted) + sigmoid ---
    seg_pool<<<G, B, 0, stream>>>(sv, start, bc, (float*)d_out, G);
}

// Round 8
// 859.852 us; speedup vs baseline: 4.1494x; 1.1164x over previous
//
#include <hip/hip_runtime.h>
#include <math.h>

// ---------------------------------------------------------------------------
// GCN summarizer: 4x (GEMM 128x128 -> normalized-adjacency aggregate + bias
// + relu) -> segmented mean-pool -> dot Wc -> sigmoid.
// R8: GEMM via v_mfma_f32_16x16x32_bf16, LDS-free (A/B frags are 16-B global
//     loads; Wt is 32 KB L1-resident). Feature storage order = MFMA C/D
//     emission order (permutation kappa); bias/Wc indexed at permuted
//     positions; weights pre-permuted+transposed+bf16 by prep_w.
//     tbuf fp8-e4m3 (gather operand), hbuf bf16. fp32 accumulate.
// ---------------------------------------------------------------------------

#define MASK40 ((1ull << 40) - 1)

typedef float v2f __attribute__((ext_vector_type(2)));
typedef __bf16 bf16x8 __attribute__((ext_vector_type(8)));
typedef float f32x4 __attribute__((ext_vector_type(4)));

__device__ inline unsigned f2bf(float x) {            // round-to-nearest-even
    unsigned u = __float_as_uint(x);
    return (u + 0x7FFFu + ((u >> 16) & 1u)) >> 16;
}

__global__ void init_packed(unsigned long long* packed, int n) {
    int i = blockIdx.x * blockDim.x + threadIdx.x;
    if (i < n) packed[i] = 0ull;
}

// one u64 atomic per edge: high 24 bits = count, low 40 = sum(ew) in 2^-24 fx.
// returned old value gives this edge's rank among same-dst edges -> slot[e].
__global__ void edge_pass(const int* __restrict__ dst, const float* __restrict__ ew,
                          unsigned long long* packed, unsigned short* __restrict__ slot,
                          int E) {
    int e = blockIdx.x * blockDim.x + threadIdx.x;
    if (e < E) {
        int d = dst[e];
        unsigned int fx = (unsigned int)rintf(ew[e] * 16777216.0f);
        unsigned long long old =
            atomicAdd(&packed[d], (1ull << 40) | (unsigned long long)fx);
        slot[e] = (unsigned short)(old >> 40);
    }
}

__global__ void dinv_cnt_k(const unsigned long long* __restrict__ packed,
                           float* dinv, int* cnt, int n) {
    int i = blockIdx.x * blockDim.x + threadIdx.x;
    if (i < n) {
        unsigned long long p = packed[i];
        float deg = 1.0f + (float)(p & MASK40) * (1.0f / 16777216.0f);
        dinv[i] = rsqrtf(deg);
        cnt[i] = (int)(p >> 40);
    }
}

// two-level exclusive scan over L[i] = cnt[i]+1 (i<N), 0 otherwise; total N+1
__global__ __launch_bounds__(1024) void scan1(const int* __restrict__ cnt, int* rowp,
                                              int* bsums, int total, int N) {
    __shared__ int sh[1024];
    int i = blockIdx.x * 1024 + threadIdx.x;
    int v = 0;
    if (i < N) v = cnt[i] + 1;
    sh[threadIdx.x] = v;
    __syncthreads();
    for (int off = 1; off < 1024; off <<= 1) {
        int t = (threadIdx.x >= (unsigned)off) ? sh[threadIdx.x - off] : 0;
        __syncthreads();
        sh[threadIdx.x] += t;
        __syncthreads();
    }
    if (i < total) rowp[i] = sh[threadIdx.x] - v;      // exclusive, pre-offset
    if (threadIdx.x == 1023) bsums[blockIdx.x] = sh[1023];
}

__global__ void scan2(int* bsums, int nb) {
    if (threadIdx.x == 0 && blockIdx.x == 0) {
        int run = 0;
        for (int b = 0; b < nb; ++b) { int t = bsums[b]; bsums[b] = run; run += t; }
    }
}

__global__ __launch_bounds__(1024) void scan3(int* rowp, const int* __restrict__ bsums,
                                              int total) {
    int i = blockIdx.x * 1024 + threadIdx.x;
    if (i < total) rowp[i] += bsums[blockIdx.x];
}

__global__ void selfloop_k(const int* __restrict__ rowp, const float* __restrict__ dinv,
                           int2* colval, int n) {
    int i = blockIdx.x * blockDim.x + threadIdx.x;
    if (i < n) {
        float dv = dinv[i];
        int2 cv;
        cv.x = i;
        cv.y = __float_as_int(dv * dv);   // dinv[i] * 1.0 * dinv[i]
        colval[rowp[i]] = cv;
    }
}

// atomic-free scatter: one 8-B write per edge (col+val interleaved).
__global__ void scatter2(const int* __restrict__ src, const int* __restrict__ dst,
                         const float* __restrict__ ew,
                         const unsigned short* __restrict__ slot,
                         const float* __restrict__ dinv, const int* __restrict__ rowp,
                         int2* colval, int E) {
    int e = blockIdx.x * blockDim.x + threadIdx.x;
    if (e < E) {
        int s = src[e], d = dst[e];
        int idx = rowp[d] + 1 + (int)slot[e];
        int2 cv;
        cv.x = s;
        cv.y = __float_as_int(dinv[s] * ew[e] * dinv[d]);
        colval[idx] = cv;
    }
}

// x fp32 -> packed bf16 (natural feature order), one uint per thread.
__global__ void cvt_x(const float2* __restrict__ x, unsigned* __restrict__ xb,
                      long n64) {
    long t = (long)blockIdx.x * 256 + threadIdx.x;
    if (t < n64) {
        float2 f = x[t];
        xb[t] = f2bf(f.x) | (f2bf(f.y) << 16);
    }
}

// Wt[l][c*128 + p] = bf16( W_l[ kappa_l(p) ][ c ] ); kappa_1 = identity,
// kappa_{2,3,4}(p) = 16*(4s+jj)+i with p=2t+h, i=t>>2, s=(t>>1)&1, jj=2(t&1)+h.
// grid (128, 4) x 128 threads.
__global__ void prep_w(const float* __restrict__ Wa, const float* __restrict__ Wb,
                       const float* __restrict__ Wc, const float* __restrict__ Wd,
                       unsigned short* __restrict__ Wt) {
    const int l = blockIdx.y;
    const float* W = (l == 0) ? Wa : (l == 1) ? Wb : (l == 2) ? Wc : Wd;
    const int c = blockIdx.x, p = threadIdx.x;
    int k;
    if (l == 0) {
        k = p;
    } else {
        int t = p >> 1, h = p & 1;
        int i = t >> 2, s = (t >> 1) & 1, jj = 2 * (t & 1) + h;
        k = 16 * (4 * s + jj) + i;
    }
    float v = W[k * 128 + c];
    unsigned u = __float_as_uint(v);
    Wt[l * 16384 + c * 128 + p] = (unsigned short)((u + 0x7FFFu + ((u >> 16) & 1u)) >> 16);
}

// ---------------------------------------------------------------------------
// MFMA GEMM: C[n,128] = A[n,128] @ W. A: packed bf16 rows (16 uint4). Wt:
// bf16 [col][k] (16 uint4 per col, 32 KB total -> L1-resident). C: fp8 rows
// (16 uint2). Block 256 thr = 4 waves; wave owns 16 rows x 128 cols.
// a-frag A[m=lane&15][k0..k0+8]; b-frag Wt[col=ct*16+(lane&15)][k0..k0+8];
// C/D: col=lane&15, row=quad*4+reg. Epilogue emits the kappa byte order.
// ---------------------------------------------------------------------------
__global__ __launch_bounds__(256) void gemm_mfma(const uint4* __restrict__ A,
                                                 const uint4* __restrict__ Wt,
                                                 uint2* __restrict__ C) {
    const int w = threadIdx.x >> 6;
    const int lane = threadIdx.x & 63;
    const int i = lane & 15, q = lane >> 4;
    const long row_base = (long)blockIdx.x * 64 + w * 16;

    f32x4 acc[8];
#pragma unroll
    for (int t = 0; t < 8; ++t) acc[t] = (f32x4){0.f, 0.f, 0.f, 0.f};

    const uint4* Arow = A + (row_base + i) * 16 + q;   // + ks*4 per k-step
#pragma unroll
    for (int ks = 0; ks < 4; ++ks) {
        const bf16x8 af = __builtin_bit_cast(bf16x8, Arow[ks * 4]);
#pragma unroll
        for (int ct = 0; ct < 8; ++ct) {
            const bf16x8 bf = __builtin_bit_cast(
                bf16x8, Wt[(size_t)(ct * 16 + i) * 16 + ks * 4 + q]);
            acc[ct] = __builtin_amdgcn_mfma_f32_16x16x32_bf16(af, bf, acc[ct], 0, 0, 0);
        }
    }

#pragma unroll
    for (int reg = 0; reg < 4; ++reg) {
        int d0 = __builtin_amdgcn_cvt_pk_fp8_f32(acc[0][reg], acc[1][reg], 0, false);
        d0     = __builtin_amdgcn_cvt_pk_fp8_f32(acc[2][reg], acc[3][reg], d0, true);
        int d1 = __builtin_amdgcn_cvt_pk_fp8_f32(acc[4][reg], acc[5][reg], 0, false);
        d1     = __builtin_amdgcn_cvt_pk_fp8_f32(acc[6][reg], acc[7][reg], d1, true);
        const long row = row_base + q * 4 + reg;
        uint2 o; o.x = (unsigned)d0; o.y = (unsigned)d1;
        C[row * 16 + i] = o;
    }
}

// permuted positions for the feature pair a lane holds (stored bytes 2l,2l+1)
__device__ inline int perm_f0(int lane) {
    return 64 * ((lane >> 1) & 1) + 32 * (lane & 1) + (lane >> 2);
}

// ---------------------------------------------------------------------------
// Aggregate: out[v] = relu( sum_e val*tin[col] + bias ). tin packed fp8
// (128 B/row, kappa order) -> one ushort/lane per edge; HW cvt; fp32 acc.
// Writes packed-bf16 activations (same kappa order). One node / 64-thr block.
// ---------------------------------------------------------------------------
__global__ __launch_bounds__(64) void aggregate(const unsigned short* __restrict__ t8,
                                                const int* __restrict__ rowp,
                                                const int2* __restrict__ colval,
                                                const float* __restrict__ bias,
                                                unsigned* __restrict__ out16, int n) {
    const int v = blockIdx.x;
    const int lane = threadIdx.x;
    const int e0 = rowp[v], e1 = rowp[v + 1];
    float ax = 0.f, ay = 0.f;
    int e = e0;
    for (; e + 4 <= e1; e += 4) {
        const int2 cv0 = colval[e],     cv1 = colval[e + 1];
        const int2 cv2 = colval[e + 2], cv3 = colval[e + 3];
        const unsigned short u0 = t8[(size_t)cv0.x * 64 + lane];
        const unsigned short u1 = t8[(size_t)cv1.x * 64 + lane];
        const unsigned short u2 = t8[(size_t)cv2.x * 64 + lane];
        const unsigned short u3 = t8[(size_t)cv3.x * 64 + lane];
        const float w0 = __int_as_float(cv0.y), w1 = __int_as_float(cv1.y);
        const float w2 = __int_as_float(cv2.y), w3 = __int_as_float(cv3.y);
        const v2f h0 = __builtin_amdgcn_cvt_pk_f32_fp8((int)u0, false);
        const v2f h1 = __builtin_amdgcn_cvt_pk_f32_fp8((int)u1, false);
        const v2f h2 = __builtin_amdgcn_cvt_pk_f32_fp8((int)u2, false);
        const v2f h3 = __builtin_amdgcn_cvt_pk_f32_fp8((int)u3, false);
        ax = fmaf(w0, h0.x, ax); ay = fmaf(w0, h0.y, ay);
        ax = fmaf(w1, h1.x, ax); ay = fmaf(w1, h1.y, ay);
        ax = fmaf(w2, h2.x, ax); ay = fmaf(w2, h2.y, ay);
        ax = fmaf(w3, h3.x, ax); ay = fmaf(w3, h3.y, ay);
    }
    for (; e < e1; ++e) {
        const int2 cv = colval[e];
        const v2f hv = __builtin_amdgcn_cvt_pk_f32_fp8(
            (int)t8[(size_t)cv.x * 64 + lane], false);
        const float w = __int_as_float(cv.y);
        ax = fmaf(w, hv.x, ax); ay = fmaf(w, hv.y, ay);
    }
    const int f0 = perm_f0(lane);
    const float rx = fmaxf(ax + bias[f0], 0.f);
    const float ry = fmaxf(ay + bias[f0 + 16], 0.f);
    out16[(size_t)v * 64 + lane] = f2bf(rx) | (f2bf(ry) << 16);
}

// last layer: gather as above, dot with Wc + wave reduce -> sv[v] (4 B).
__global__ __launch_bounds__(64) void aggregate_last(const unsigned short* __restrict__ t8,
                                                     const int* __restrict__ rowp,
                                                     const int2* __restrict__ colval,
                                                     const float* __restrict__ bias,
                                                     const float* __restrict__ Wc,
                                                     float* __restrict__ sv, int n) {
    const int v = blockIdx.x;
    const int lane = threadIdx.x;
    const int e0 = rowp[v], e1 = rowp[v + 1];
    float ax = 0.f, ay = 0.f;
    int e = e0;
    for (; e + 4 <= e1; e += 4) {
        const int2 cv0 = colval[e],     cv1 = colval[e + 1];
        const int2 cv2 = colval[e + 2], cv3 = colval[e + 3];
        const unsigned short u0 = t8[(size_t)cv0.x * 64 + lane];
        const unsigned short u1 = t8[(size_t)cv1.x * 64 + lane];
        const unsigned short u2 = t8[(size_t)cv2.x * 64 + lane];
        const unsigned short u3 = t8[(size_t)cv3.x * 64 + lane];
        const float w0 = __int_as_float(cv0.y), w1 = __int_as_float(cv1.y);
        const float w2 = __int_as_float(cv2.y), w3 = __int_as_float(cv3.y);
        const v2f h0 = __builtin_amdgcn_cvt_pk_f32_fp8((int)u0, false);
        const v2f h1 = __builtin_amdgcn_cvt_pk_f32_fp8((int)u1, false);
        const v2f h2 = __builtin_amdgcn_cvt_pk_f32_fp8((int)u2, false);
        const v2f h3 = __builtin_amdgcn_cvt_pk_f32_fp8((int)u3, false);
        ax = fmaf(w0, h0.x, ax); ay = fmaf(w0, h0.y, ay);
        ax = fmaf(w1, h1.x, ax); ay = fmaf(w1, h1.y, ay);
        ax = fmaf(w2, h2.x, ax); ay = fmaf(w2, h2.y, ay);
        ax = fmaf(w3, h3.x, ax); ay = fmaf(w3, h3.y, ay);
    }
    for (; e < e1; ++e) {
        const int2 cv = colval[e];
        const v2f hv = __builtin_amdgcn_cvt_pk_f32_fp8(
            (int)t8[(size_t)cv.x * 64 + lane], false);
        const float w = __int_as_float(cv.y);
        ax = fmaf(w, hv.x, ax); ay = fmaf(w, hv.y, ay);
    }
    const int f0 = perm_f0(lane);
    float p = fmaxf(ax + bias[f0], 0.f) * Wc[f0] +
              fmaxf(ay + bias[f0 + 16], 0.f) * Wc[f0 + 16];
#pragma unroll
    for (int off = 32; off; off >>= 1) p += __shfl_down(p, off);
    if (lane == 0) sv[v] = p;
}

// start[g] = lower_bound(batch, g) for g in [0, G]; batch is sorted.
__global__ void gstart_k(const int* __restrict__ batch, int* start, int N, int G) {
    int g = blockIdx.x * blockDim.x + threadIdx.x;
    if (g <= G) {
        int lo = 0, hi = N;
        while (lo < hi) {
            int mid = (lo + hi) >> 1;
            if (batch[mid] < g) lo = mid + 1; else hi = mid;
        }
        start[g] = lo;
    }
}

// one block per graph: mean of sv over the (contiguous) segment, sigmoid.
__global__ __launch_bounds__(256) void seg_pool(const float* __restrict__ sv,
                                                const int* __restrict__ start,
                                                const float* __restrict__ bc,
                                                float* __restrict__ out, int G) {
    __shared__ float sh[4];
    const int g = blockIdx.x;
    const int s = start[g], epos = start[g + 1];
    float acc = 0.f;
    for (int i = s + threadIdx.x; i < epos; i += 256) acc += sv[i];
#pragma unroll
    for (int off = 32; off; off >>= 1) acc += __shfl_down(acc, off);
    if ((threadIdx.x & 63) == 0) sh[threadIdx.x >> 6] = acc;
    __syncthreads();
    if (threadIdx.x == 0) {
        float sum = sh[0] + sh[1] + sh[2] + sh[3];
        float cnt = (float)(epos - s);
        float z = sum / fmaxf(cnt, 1.0f) + bc[0];
        out[g] = 1.0f / (1.0f + expf(-z));
    }
}

extern "C" void kernel_launch(void* const* d_in, const int* in_sizes, int n_in,
                              void* d_out, int out_size, void* d_ws, size_t ws_size,
                              hipStream_t stream) {
    const float* x   = (const float*)d_in[0];
    const int* ei    = (const int*)d_in[1];
    const float* ew  = (const float*)d_in[2];
    const int* batch = (const int*)d_in[3];
    const float* W1 = (const float*)d_in[4];  const float* b1 = (const float*)d_in[5];
    const float* W2 = (const float*)d_in[6];  const float* b2 = (const float*)d_in[7];
    const float* W3 = (const float*)d_in[8];  const float* b3 = (const float*)d_in[9];
    const float* W4 = (const float*)d_in[10]; const float* b4 = (const float*)d_in[11];
    const float* Wc = (const float*)d_in[12]; const float* bc = (const float*)d_in[13];

    const int N = in_sizes[0] / 128;
    const int E = in_sizes[2];
    const int G = out_size;
    const int* src = ei;
    const int* dst = ei + E;
    const int nblk = (N + 63) / 64;
    const long Npad = (long)nblk * 64;

    // workspace carve (re-poisoned each call; everything read is written below
    // or harmlessly finite-garbage in pad rows)
    char* p = (char*)d_ws;
    auto alloc = [&](size_t bytes) {
        void* q = (void*)p;
        p += (bytes + 255) & ~(size_t)255;
        return q;
    };
    unsigned long long* packed = (unsigned long long*)alloc((size_t)N * 8);
    float* dinv = (float*)alloc((size_t)N * 4);
    int* cnt    = (int*)alloc((size_t)N * 4);
    unsigned short* slot = (unsigned short*)alloc((size_t)E * 2);
    int* rowp   = (int*)alloc((size_t)(N + 1) * 4);
    int* bsums  = (int*)alloc(1024 * 4);
    const size_t M = (size_t)E + (size_t)N;
    int2* colval = (int2*)alloc(M * 8);
    unsigned* tbuf = (unsigned*)alloc((size_t)Npad * 32 * 4);  // fp8 GEMM out
    unsigned* hbuf = (unsigned*)alloc((size_t)Npad * 64 * 4);  // bf16 activations
    unsigned* xb   = (unsigned*)alloc((size_t)Npad * 64 * 4);  // bf16 copy of x
    unsigned short* Wt = (unsigned short*)alloc(4 * 16384 * 2); // bf16 Wt[4]
    float* sv   = (float*)alloc((size_t)N * 4);
    int* start  = (int*)alloc((size_t)(G + 1) * 4);

    const int B = 256;
    // --- graph normalization + CSR build (one atomic per edge total) ---
    init_packed<<<(N + B - 1) / B, B, 0, stream>>>(packed, N);
    edge_pass<<<(E + B - 1) / B, B, 0, stream>>>(dst, ew, packed, slot, E);
    dinv_cnt_k<<<(N + B - 1) / B, B, 0, stream>>>(packed, dinv, cnt, N);
    const int total = N + 1;
    const int nb = (total + 1023) / 1024;
    scan1<<<nb, 1024, 0, stream>>>(cnt, rowp, bsums, total, N);
    scan2<<<1, 64, 0, stream>>>(bsums, nb);
    scan3<<<nb, 1024, 0, stream>>>(rowp, bsums, total);
    selfloop_k<<<(N + B - 1) / B, B, 0, stream>>>(rowp, dinv, colval, N);
    scatter2<<<(E + B - 1) / B, B, 0, stream>>>(src, dst, ew, slot, dinv, rowp,
                                                colval, E);
    gstart_k<<<(G + 1 + B - 1) / B, B, 0, stream>>>(batch, start, N, G);

    // --- input conversion + weight prep ---
    const long n64 = (long)N * 64;
    cvt_x<<<(int)((n64 + 255) / 256), B, 0, stream>>>((const float2*)x, xb, n64);
    prep_w<<<dim3(128, 4), 128, 0, stream>>>(W1, W2, W3, W4, Wt);

    // --- 4 GCN layers ---
    const unsigned short* t8 = (const unsigned short*)tbuf;
    const uint4* Wt4 = (const uint4*)Wt;
    gemm_mfma<<<nblk, B, 0, stream>>>((const uint4*)xb,   Wt4,         (uint2*)tbuf);
    aggregate<<<N, 64, 0, stream>>>(t8, rowp, colval, b1, hbuf, N);
    gemm_mfma<<<nblk, B, 0, stream>>>((const uint4*)hbuf, Wt4 + 2048,  (uint2*)tbuf);
    aggregate<<<N, 64, 0, stream>>>(t8, rowp, colval, b2, hbuf, N);
    gemm_mfma<<<nblk, B, 0, stream>>>((const uint4*)hbuf, Wt4 + 4096,  (uint2*)tbuf);
    aggregate<<<N, 64, 0, stream>>>(t8, rowp, colval, b3, hbuf, N);
    gemm_mfma<<<nblk, B, 0, stream>>>((const uint4*)hbuf, Wt4 + 6144,  (uint2*)tbuf);
    aggregate_last<<<N, 64, 0, stream>>>(t8, rowp, colval, b4, Wc, sv, N);

    // --- segmented mean pool (batch sorted) + sigmoid ---
    seg_pool<<<G, B, 0, stream>>>(sv, start, bc, (float*)d_out, G);
}